// Round 12
// baseline (163.580 us; speedup 1.0000x reference)
//
#include <hip/hip_runtime.h>

// SelfCorrelationPercPooling: x (32,32,32,512) f32 ->
//   corr[b] = X·Xᵀ/512 (1024x1024), per-row descending sort, gather 256 ranks.
// v12 = v11 with a 2-A-tile GEMM block (256 rows x 128 cols per block):
//   two A-tiles share each staged B-tile -> LDS reads per kt per wave drop from
//   9/8 MFMA to 10/16 MFMA (the measured bottleneck: ~46us of LDS-pipe time).
//   Staging swizzle, K-loop, XCD swizzle (re-derived for nwg=1024), and the
//   verified 128-run epilogue are unchanged (epilogue runs twice per lane).
// Pipeline: cvt(bf16) -> corr_gemm_tiled -> sort_rows (2 rows/wave) -> out.
// Fallbacks: ws>=32MB -> v5 fused kernel; else v1 fp32 kernel.

#define NMAPS 1024
#define FDIM 512
#define TM 16
#define NT 256

typedef __attribute__((ext_vector_type(8))) short short8_t;  // bf16x8 MFMA frag
typedef __attribute__((ext_vector_type(4))) float f32x4;
typedef _Float16 h2 __attribute__((ext_vector_type(2)));     // packed fp16 pair

#define SELD 0x03020504u  // perm selector: (mx.lo16, mn.hi16) = desc pair
#define SELA 0x07060100u  // perm selector: (mn.lo16, mx.hi16) = asc pair

__device__ __forceinline__ h2 h2min(h2 a, h2 b) { return __builtin_elementwise_min(a, b); }
__device__ __forceinline__ h2 h2max(h2 a, h2 b) { return __builtin_elementwise_max(a, b); }

__device__ __forceinline__ unsigned h2u(h2 x) { union { h2 h; unsigned u; } t; t.h = x; return t.u; }
__device__ __forceinline__ h2 u2h(unsigned x) { union { h2 h; unsigned u; } t; t.u = x; return t.h; }

__device__ __forceinline__ h2 h2swap(h2 v) {
  unsigned u = h2u(v);
  return u2h((u >> 16) | (u << 16));
}

__device__ __forceinline__ h2 h2shfl_xor(h2 v, int m) {
  union { h2 h; int i; } u;
  u.h = v;
  u.i = __shfl_xor(u.i, m, 64);
  return u.h;
}

// packed word-pair CE, runtime direction
__device__ __forceinline__ void ce_pair(h2& a, h2& b, bool d) {
  h2 mn = h2min(a, b), mx = h2max(a, b);
  a = d ? mx : mn;
  b = d ? mn : mx;
}

// within-word CE (element stride 1) via perm selector (sel = SELD or SELA)
__device__ __forceinline__ h2 ce1(h2 w, unsigned sel) {
  h2 s = h2swap(w);
  h2 mn = h2min(w, s), mx = h2max(w, s);
#if __has_builtin(__builtin_amdgcn_perm)
  return u2h(__builtin_amdgcn_perm(h2u(mx), h2u(mn), sel));
#else
  h2 rd; rd[0] = mx[0]; rd[1] = mn[1];
  h2 ra; ra[0] = mn[0]; ra[1] = mx[1];
  return (sel == SELD) ? rd : ra;
#endif
}

// intra-lane merge of a 16-run (levels j=8,4,2,1), uniform direction d
__device__ __forceinline__ void intra_merge16(h2 w[8], bool d, unsigned sel) {
  ce_pair(w[0], w[4], d); ce_pair(w[1], w[5], d); ce_pair(w[2], w[6], d); ce_pair(w[3], w[7], d);
  ce_pair(w[0], w[2], d); ce_pair(w[1], w[3], d); ce_pair(w[4], w[6], d); ce_pair(w[5], w[7], d);
  ce_pair(w[0], w[1], d); ce_pair(w[2], w[3], d); ce_pair(w[4], w[5], d); ce_pair(w[6], w[7], d);
#pragma unroll
  for (int u = 0; u < 8; ++u) w[u] = ce1(w[u], sel);
}

// full bitonic sort of 16 in-lane elements, overall direction d  [verified v8/v9]
__device__ __forceinline__ void sort16(h2 w[8], bool d, unsigned sd, unsigned si) {
  w[0] = ce1(w[0], sd); w[1] = ce1(w[1], si); w[2] = ce1(w[2], sd); w[3] = ce1(w[3], si);
  w[4] = ce1(w[4], sd); w[5] = ce1(w[5], si); w[6] = ce1(w[6], sd); w[7] = ce1(w[7], si);
  ce_pair(w[0], w[1], d); ce_pair(w[2], w[3], !d); ce_pair(w[4], w[5], d); ce_pair(w[6], w[7], !d);
  w[0] = ce1(w[0], sd); w[1] = ce1(w[1], sd); w[2] = ce1(w[2], si); w[3] = ce1(w[3], si);
  w[4] = ce1(w[4], sd); w[5] = ce1(w[5], sd); w[6] = ce1(w[6], si); w[7] = ce1(w[7], si);
  ce_pair(w[0], w[2], d); ce_pair(w[1], w[3], d); ce_pair(w[4], w[6], !d); ce_pair(w[5], w[7], !d);
  ce_pair(w[0], w[1], d); ce_pair(w[2], w[3], d); ce_pair(w[4], w[5], !d); ce_pair(w[6], w[7], !d);
  w[0] = ce1(w[0], sd); w[1] = ce1(w[1], sd); w[2] = ce1(w[2], sd); w[3] = ce1(w[3], sd);
  w[4] = ce1(w[4], si); w[5] = ce1(w[5], si); w[6] = ce1(w[6], si); w[7] = ce1(w[7], si);
  intra_merge16(w, d, sd);
}

// in-lane bitonic merge of 32 elements (16 words), uniform direction d
__device__ __forceinline__ void merge32(h2 w[16], bool d) {
  const unsigned sel = d ? SELD : SELA;
#pragma unroll
  for (int u = 0; u < 8; ++u) ce_pair(w[u], w[u + 8], d);          // j=16
#pragma unroll
  for (int u = 0; u < 16; ++u)
    if ((u & 4) == 0) ce_pair(w[u], w[u | 4], d);                  // j=8
#pragma unroll
  for (int u = 0; u < 16; ++u)
    if ((u & 2) == 0) ce_pair(w[u], w[u | 2], d);                  // j=4
#pragma unroll
  for (int u = 0; u < 16; ++u)
    if ((u & 1) == 0) ce_pair(w[u], w[u | 1], d);                  // j=2
#pragma unroll
  for (int u = 0; u < 16; ++u) w[u] = ce1(w[u], sel);              // j=1
}

// cross-lane CE over N words (shuffle mask m), uniform keepmax
template<int N>
__device__ __forceinline__ void cross_ceN(h2* w, int m, bool keepmax) {
#pragma unroll
  for (int u = 0; u < N; ++u) {
    h2 p = h2shfl_xor(w[u], m);
    h2 mn = h2min(w[u], p), mx = h2max(w[u], p);
    w[u] = keepmax ? mx : mn;
  }
}
__device__ __forceinline__ void cross_ce(h2 w[8], int m, bool keepmax) {
  cross_ceN<8>(w, m, keepmax);
}

// One bitonic stage (block size K) on 1024 elements held as 8 h2/lane.
// Element i = lane*16 + 2*u + h. desc = ((i & K) == 0). [verified v5/v6/v7]
template<int K>
__device__ __forceinline__ void bitonic_stage(h2 w8[8], int lane) {
  const bool laneDesc = (K >= 16) ? ((lane & (K >> 4)) == 0) : true;
#pragma unroll
  for (int j = 512; j >= 16; j >>= 1) {
    if (j > (K >> 1)) continue;
    const int m = j >> 4;
    const bool keepmax = (((lane & m) == 0) == laneDesc);
#pragma unroll
    for (int u = 0; u < 8; ++u) {
      h2 p = h2shfl_xor(w8[u], m);
      h2 mn = h2min(w8[u], p), mx = h2max(w8[u], p);
      w8[u] = keepmax ? mx : mn;
    }
  }
#pragma unroll
  for (int j = 8; j >= 2; j >>= 1) {
    if (j > (K >> 1)) continue;
    const int jw = j >> 1;
#pragma unroll
    for (int u = 0; u < 8; ++u) {
      if ((u & jw) == 0) {
        const int v = u | jw;
        const bool desc = (K <= 8) ? (((2 * u) & K) == 0) : laneDesc;
        h2 mn = h2min(w8[u], w8[v]), mx = h2max(w8[u], w8[v]);
        w8[u] = desc ? mx : mn;
        w8[v] = desc ? mn : mx;
      }
    }
  }
#pragma unroll
  for (int u = 0; u < 8; ++u) {
    const bool desc = (K <= 8) ? (((2 * u) & K) == 0) : laneDesc;
    h2 s = h2swap(w8[u]);
    h2 mn = h2min(w8[u], s), mx = h2max(w8[u], s);
    h2 rd = (h2){mx[0], mn[1]};
    h2 ra = (h2){mn[0], mx[1]};
    w8[u] = desc ? rd : ra;
  }
}

// tail stage (K >= 128 only), TWO independent rows interleaved for ILP
template<int K>
__device__ __forceinline__ void bitonic_stage_tail2(h2 A[8], h2 B[8], int lane) {
  const bool laneDesc = ((lane & (K >> 4)) == 0);
#pragma unroll
  for (int j = 512; j >= 16; j >>= 1) {
    if (j > (K >> 1)) continue;
    const int m = j >> 4;
    const bool km = (((lane & m) == 0) == laneDesc);
    cross_ce(A, m, km);
    cross_ce(B, m, km);
  }
  const unsigned sel = laneDesc ? SELD : SELA;
  intra_merge16(A, laneDesc, sel);
  intra_merge16(B, laneDesc, sel);
}

__device__ __forceinline__ void run_bitonic(h2 w8[8], int lane) {  // full (fallbacks)
  bitonic_stage<2>(w8, lane);
  bitonic_stage<4>(w8, lane);
  bitonic_stage<8>(w8, lane);
  bitonic_stage<16>(w8, lane);
  bitonic_stage<32>(w8, lane);
  bitonic_stage<64>(w8, lane);
  bitonic_stage<128>(w8, lane);
  bitonic_stage<256>(w8, lane);
  bitonic_stage<512>(w8, lane);
  bitonic_stage<1024>(w8, lane);
}

// ---------------- fp32 -> bf16 (RNE) conversion pre-pass ----------------
__global__ __launch_bounds__(256) void cvt_bf16_kernel(const float* __restrict__ x,
                                                       short* __restrict__ xw, int n8) {
  int i = blockIdx.x * 256 + threadIdx.x;
  if (i >= n8) return;
  const float4* x4 = reinterpret_cast<const float4*>(x);
  float4 a = x4[i * 2], c = x4[i * 2 + 1];
  float f[8] = {a.x, a.y, a.z, a.w, c.x, c.y, c.z, c.w};
  union { short8_t v; short s[8]; } o;
#pragma unroll
  for (int j = 0; j < 8; ++j) {
    unsigned u = __float_as_uint(f[j]);
    u += 0x7fffu + ((u >> 16) & 1u);  // RNE (no NaN in data)
    o.s[j] = (short)(u >> 16);
  }
  reinterpret_cast<short8_t*>(xw)[i] = o.v;
}

// ---------------- kernel 2: TILED MFMA GEMM, 2 A-tiles per block ----------------
// Block = 256 rows x 128 cols (two 128-row A-tiles share one B-tile). BK=32,
// double-buffered staging with source swizzle s^=(r>>1)&3 (verified v9/v10).
// Per kt per wave: 2 A-reads + 8 B-reads for 16 MFMAs. Epilogue: verified
// 128-run network (v10), executed once per A-tile. UNSCALED fp16 -> ws.
__global__ __launch_bounds__(512) void corr_gemm_tiled(const short* __restrict__ xw,
                                                       unsigned* __restrict__ corrW) {
  __shared__ short Asm[2][2][128 * 32];  // [buf][tile] 2 x 2 x 8 KB = 32 KB
  __shared__ short Bsm[2][128 * 32];     // [buf]       2 x 8 KB      = 16 KB
  const int tid = threadIdx.x;
  int b, tile;
  if (gridDim.x == 1024) {
    const int bid = blockIdx.x;
    const int xcd = bid & 7;       // dispatch round-robins across 8 XCDs
    const int j = bid >> 3;        // 0..127
    b = (j >> 5) * 8 + xcd;        // 4 batches per XCD -> L2-resident panels
    tile = j & 31;
  } else {
    b = blockIdx.x >> 5;
    tile = blockIdx.x & 31;
  }
  const int it2 = tile >> 3, jt = tile & 7;
  const int i0 = it2 * 256, j0 = jt * 128;
  const int lane = tid & 63;
  const int w = tid >> 6;     // wave 0..7
  const int lr = lane & 15;
  const int kg = lane >> 4;   // 0..3
  const short* Xb = xw + (size_t)b * NMAPS * FDIM;

  // staging: per kt each thread stages 1 chunk of B and 1 chunk of EACH A-tile
  const int sr = tid >> 2;
  const int ss = (tid & 3) ^ ((sr >> 1) & 3);  // pre-swizzled source chunk
  const int srcOff = sr * FDIM + ss * 8;
  const int dstOff = tid * 8;                  // shorts

  // read offsets (short units); same formula for both A-tiles (per-tile base)
  const int rowa = w * 16 + lr;
  const int aOff = rowa * 32 + (kg ^ ((rowa >> 1) & 3)) * 8;
  int bOff[8];
#pragma unroll
  for (int fn = 0; fn < 8; ++fn) {
    const int rowb = fn * 16 + lr;
    bOff[fn] = rowb * 32 + (kg ^ ((rowb >> 1) & 3)) * 8;
  }

  f32x4 acc0[8], acc1[8];
#pragma unroll
  for (int fn = 0; fn < 8; ++fn) {
    acc0[fn] = (f32x4){0.f, 0.f, 0.f, 0.f};
    acc1[fn] = (f32x4){0.f, 0.f, 0.f, 0.f};
  }

#define STAGE(buf, kt)                                                                \
  {                                                                                   \
    const short* gA0 = Xb + (size_t)i0 * FDIM + srcOff + (kt) * 32;                   \
    const short* gA1 = Xb + (size_t)(i0 + 128) * FDIM + srcOff + (kt) * 32;           \
    const short* gB = Xb + (size_t)j0 * FDIM + srcOff + (kt) * 32;                    \
    __builtin_amdgcn_global_load_lds(                                                 \
        (const __attribute__((address_space(1))) unsigned*)gA0,                       \
        (__attribute__((address_space(3))) unsigned*)(Asm[buf][0] + dstOff), 16, 0,   \
        0);                                                                           \
    __builtin_amdgcn_global_load_lds(                                                 \
        (const __attribute__((address_space(1))) unsigned*)gA1,                       \
        (__attribute__((address_space(3))) unsigned*)(Asm[buf][1] + dstOff), 16, 0,   \
        0);                                                                           \
    __builtin_amdgcn_global_load_lds(                                                 \
        (const __attribute__((address_space(1))) unsigned*)gB,                        \
        (__attribute__((address_space(3))) unsigned*)(Bsm[buf] + dstOff), 16, 0, 0);  \
  }

  STAGE(0, 0);
  __syncthreads();  // buf0 ready

  for (int kt = 0; kt < 16; ++kt) {
    const int cur = kt & 1;
    if (kt < 15) STAGE(cur ^ 1, kt + 1);  // prefetch next tile into other buffer

    short8_t a0 = *reinterpret_cast<const short8_t*>(Asm[cur][0] + aOff);
    short8_t a1 = *reinterpret_cast<const short8_t*>(Asm[cur][1] + aOff);
    short8_t bf[8];
#pragma unroll
    for (int fn = 0; fn < 8; ++fn)
      bf[fn] = *reinterpret_cast<const short8_t*>(Bsm[cur] + bOff[fn]);
#pragma unroll
    for (int fn = 0; fn < 8; ++fn) {
      acc0[fn] = __builtin_amdgcn_mfma_f32_16x16x32_bf16(bf[fn], a0, acc0[fn], 0, 0, 0);
      acc1[fn] = __builtin_amdgcn_mfma_f32_16x16x32_bf16(bf[fn], a1, acc1[fn], 0, 0, 0);
    }

    __syncthreads();  // next buffer staged; everyone done reading cur
  }
#undef STAGE

  // ---- epilogue (x2): lane's 32 values (row, cols j0+{fn*16+kg*4+reg}) ->
  //      sorted 128-run. Canonical dirs: desc=((i&K)==0); i bit5..6 = kg bits,
  //      i bit7 = jt&1. UNSCALED (scale deferred to scatter).  [verified v10]
  const bool D128 = ((jt & 1) == 0);
  const bool d64 = ((kg & 2) == 0);
  const bool d32 = ((kg & 1) == 0);
#pragma unroll
  for (int t2 = 0; t2 < 2; ++t2) {
    const f32x4* acc = (t2 == 0) ? acc0 : acc1;
    h2 W[16];
#pragma unroll
    for (int fn = 0; fn < 8; ++fn) {
      W[2 * fn] = (h2){(_Float16)acc[fn][0], (_Float16)acc[fn][1]};
      W[2 * fn + 1] = (h2){(_Float16)acc[fn][2], (_Float16)acc[fn][3]};
    }
    sort16(W, true, SELD, SELA);
    sort16(W + 8, false, SELA, SELD);
    merge32(W, d32);
    cross_ceN<16>(W, 16, d32 == d64);
    merge32(W, d64);
    cross_ceN<16>(W, 32, d64 == D128);
    cross_ceN<16>(W, 16, d32 == D128);
    merge32(W, D128);
    const size_t roww = ((size_t)b * NMAPS + i0 + t2 * 128 + w * 16 + lr) * 512;
    const int wq = (j0 >> 1) + kg * 16;
    union { h2 h[4]; uint4 u; } s0, s1, s2, s3;
#pragma unroll
    for (int q = 0; q < 4; ++q) { s0.h[q] = W[q]; s1.h[q] = W[4 + q]; s2.h[q] = W[8 + q]; s3.h[q] = W[12 + q]; }
    *reinterpret_cast<uint4*>(corrW + roww + wq) = s0.u;
    *reinterpret_cast<uint4*>(corrW + roww + wq + 4) = s1.u;
    *reinterpret_cast<uint4*>(corrW + roww + wq + 8) = s2.u;
    *reinterpret_cast<uint4*>(corrW + roww + wq + 12) = s3.u;
  }
}

// ---------------- kernel 3: tail sort (K=256..1024), TWO rows per wave + scatter ----------------
__global__ __launch_bounds__(256) void sort_rows_kernel(const unsigned* __restrict__ corrW,
                                                        float* __restrict__ out) {
  const int tid = threadIdx.x;
  const int lane = tid & 63;
  const int rA = blockIdx.x * 8 + (tid >> 6) * 2;  // wave handles rows rA, rA+1
  const int rB = rA + 1;
  const uint4* pa = reinterpret_cast<const uint4*>(corrW + (size_t)rA * 512);
  const uint4* pb = reinterpret_cast<const uint4*>(corrW + (size_t)rB * 512);

  h2 A[8], B[8];
  {
    union { uint4 u; h2 h[4]; } t0, t1;
    t0.u = pa[lane * 2]; t1.u = pa[lane * 2 + 1];
    A[0] = t0.h[0]; A[1] = t0.h[1]; A[2] = t0.h[2]; A[3] = t0.h[3];
    A[4] = t1.h[0]; A[5] = t1.h[1]; A[6] = t1.h[2]; A[7] = t1.h[3];
    t0.u = pb[lane * 2]; t1.u = pb[lane * 2 + 1];
    B[0] = t0.h[0]; B[1] = t0.h[1]; B[2] = t0.h[2]; B[3] = t0.h[3];
    B[4] = t1.h[0]; B[5] = t1.h[1]; B[6] = t1.h[2]; B[7] = t1.h[3];
  }

  // input: 128-runs sorted, desc iff (c&128)==0 -> start at K=256
  bitonic_stage_tail2<256>(A, B, lane);
  bitonic_stage_tail2<512>(A, B, lane);
  bitonic_stage_tail2<1024>(A, B, lane);

  float* oa = out + (size_t)rA * 256;
  float* ob = out + (size_t)rB * 256;
#pragma unroll
  for (int u = 0; u < 8; ++u) {
#pragma unroll
    for (int hh = 0; hh < 2; ++hh) {
      const int i = lane * 16 + 2 * u + hh;
      const int p = (int)rint((double)(i - 1) * (255.0 / 1022.0));
      const int rk = (int)rint(1.0 + (double)p * (1022.0 / 255.0));
      if (rk == i) {
        oa[p] = (float)A[u][hh] * (1.f / FDIM);  // deferred scale
        ob[p] = (float)B[u][hh] * (1.f / FDIM);
      }
    }
  }
}

// ---------------- v5 fused fallback (ws >= 32MB but < 96MB) ----------------
__global__ __launch_bounds__(NT) void selfcorr_mfma_kernel(const short* __restrict__ xw,
                                                           float* __restrict__ out) {
  __shared__ alignas(16) h2 SH[TM * 512];  // 32 KB
  const int tid = threadIdx.x;
  const int b = blockIdx.y;
  const int m0 = blockIdx.x * TM;
  const int lane = tid & 63;
  const int wid = tid >> 6;
  const int lr = lane & 15;
  const int kg = lane >> 4;
  const int wc = wid * 256;
  const short* Xb = xw + (size_t)b * NMAPS * FDIM;

  f32x4 acc[16];
#pragma unroll
  for (int t = 0; t < 16; ++t) acc[t] = (f32x4){0.f, 0.f, 0.f, 0.f};

  for (int kk = 0; kk < 16; ++kk) {
    const short8_t* base = reinterpret_cast<const short8_t*>(Xb + kk * 32 + kg * 8);
    short8_t afrag = base[(size_t)(m0 + lr) * 64];
    short8_t bfrag[16];
#pragma unroll
    for (int t = 0; t < 16; ++t) bfrag[t] = base[(size_t)(wc + t * 16 + lr) * 64];
#pragma unroll
    for (int t = 0; t < 16; ++t)
      acc[t] = __builtin_amdgcn_mfma_f32_16x16x32_bf16(bfrag[t], afrag, acc[t], 0, 0, 0);
  }

  {
    const int xorv = (lr & 7) << 2;
#pragma unroll
    for (int t = 0; t < 16; ++t) {
      h2 lo = (h2){(_Float16)(acc[t][0] * (1.f / FDIM)), (_Float16)(acc[t][1] * (1.f / FDIM))};
      h2 hi = (h2){(_Float16)(acc[t][2] * (1.f / FDIM)), (_Float16)(acc[t][3] * (1.f / FDIM))};
      const int W = (wc >> 1) + t * 8 + kg * 2;
      const int phys = lr * 512 + (W ^ xorv);
      union { h2 h[2]; uint2 u; } pk;
      pk.h[0] = lo; pk.h[1] = hi;
      *reinterpret_cast<uint2*>(&SH[phys]) = pk.u;
    }
  }
  __syncthreads();

  const int rowbase = wid * 4;
  for (int rr = rowbase; rr < rowbase + 4; ++rr) {
    const int rx = (rr & 7) << 2;
    h2 w8[8];
#pragma unroll
    for (int q = 0; q < 2; ++q) {
      const int p4 = rr * 512 + ((lane * 8 + q * 4) ^ rx);
      union { uint4 u; h2 h[4]; } un;
      un.u = *reinterpret_cast<const uint4*>(&SH[p4]);
      w8[q * 4 + 0] = un.h[0]; w8[q * 4 + 1] = un.h[1];
      w8[q * 4 + 2] = un.h[2]; w8[q * 4 + 3] = un.h[3];
    }
    run_bitonic(w8, lane);
#pragma unroll
    for (int q = 0; q < 2; ++q) {
      const int p4 = rr * 512 + ((lane * 8 + q * 4) ^ rx);
      union { uint4 u; h2 h[4]; } un;
      un.h[0] = w8[q * 4 + 0]; un.h[1] = w8[q * 4 + 1];
      un.h[2] = w8[q * 4 + 2]; un.h[3] = w8[q * 4 + 3];
      *reinterpret_cast<uint4*>(&SH[p4]) = un.u;
    }
  }
  __builtin_amdgcn_wave_barrier();

#pragma unroll
  for (int i = 0; i < 16; ++i) {
    const int rr = rowbase + (i >> 2);
    const int p = lane + ((i & 3) << 6);
    const int rank = (int)rint(1.0 + (double)p * (1022.0 / 255.0));
    const int Wr = (rank >> 1) ^ ((rr & 7) << 2);
    h2 hv = SH[rr * 512 + Wr];
    out[((size_t)(b * NMAPS + m0 + rr) << 8) + p] = (float)hv[rank & 1];
  }
}

// ---------------- v1 fp32 fallback (ws too small) ----------------
__device__ __forceinline__ int sw4(int row, int c4) {
  return (row << 8) | (c4 ^ ((c4 >> 3) & 7));
}
__device__ __forceinline__ void ce(float& a, float& b, bool desc) {
  float mn = fminf(a, b);
  float mx = fmaxf(a, b);
  a = desc ? mx : mn;
  b = desc ? mn : mx;
}

__global__ __launch_bounds__(NT) void selfcorr_pool_kernel(const float* __restrict__ x,
                                                           float* __restrict__ out) {
  __shared__ float lds[TM * NMAPS];
  float4* S4 = reinterpret_cast<float4*>(lds);
  const int tid = threadIdx.x;
  const int b = blockIdx.y;
  const int m0 = blockIdx.x * TM;
  const float4* Xb = reinterpret_cast<const float4*>(x) + (size_t)b * NMAPS * (FDIM / 4);

  float4* A4 = reinterpret_cast<float4*>(lds);
#pragma unroll
  for (int idx = tid; idx < TM * (FDIM / 4); idx += NT) {
    A4[idx] = Xb[(m0 + (idx >> 7)) * 128 + (idx & 127)];
  }
  __syncthreads();

  float acc[TM][4];
#pragma unroll
  for (int m = 0; m < TM; ++m)
#pragma unroll
    for (int j = 0; j < 4; ++j) acc[m][j] = 0.0f;

  float4 nb0 = Xb[(tid + 0) * 128];
  float4 nb1 = Xb[(tid + 256) * 128];
  float4 nb2 = Xb[(tid + 512) * 128];
  float4 nb3 = Xb[(tid + 768) * 128];
  for (int k4 = 0; k4 < 128; ++k4) {
    float4 b0 = nb0, b1 = nb1, b2 = nb2, b3 = nb3;
    const int kn = (k4 < 127) ? (k4 + 1) : 127;
    nb0 = Xb[(tid + 0) * 128 + kn];
    nb1 = Xb[(tid + 256) * 128 + kn];
    nb2 = Xb[(tid + 512) * 128 + kn];
    nb3 = Xb[(tid + 768) * 128 + kn];
#pragma unroll
    for (int m = 0; m < TM; ++m) {
      float4 a = A4[m * 128 + k4];
      acc[m][0] += a.x * b0.x + a.y * b0.y + a.z * b0.z + a.w * b0.w;
      acc[m][1] += a.x * b1.x + a.y * b1.y + a.z * b1.z + a.w * b1.w;
      acc[m][2] += a.x * b2.x + a.y * b2.y + a.z * b2.z + a.w * b2.w;
      acc[m][3] += a.x * b3.x + a.y * b3.y + a.z * b3.z + a.w * b3.w;
    }
  }
  __syncthreads();

#pragma unroll
  for (int m = 0; m < TM; ++m) {
#pragma unroll
    for (int j = 0; j < 4; ++j) {
      const int n = tid + (j << 8);
      lds[sw4(m, n >> 2) * 4 + (n & 3)] = acc[m][j] * (1.0f / FDIM);
    }
  }
  __syncthreads();

#pragma unroll
  for (int c = 0; c < 2; ++c) {
    const int cid = tid + (c << 8);
    const int row = cid >> 5;
    const int chunk = cid & 31;
    float r[32];
#pragma unroll
    for (int q = 0; q < 8; ++q) {
      float4 t = S4[sw4(row, (chunk << 3) + q)];
      r[q * 4 + 0] = t.x; r[q * 4 + 1] = t.y; r[q * 4 + 2] = t.z; r[q * 4 + 3] = t.w;
    }
    const bool D = ((chunk & 1) == 0);
#pragma unroll
    for (int k2 = 2; k2 <= 32; k2 <<= 1) {
#pragma unroll
      for (int j = k2 >> 1; j > 0; j >>= 1) {
#pragma unroll
        for (int i = 0; i < 32; ++i) {
          if ((i & j) == 0) ce(r[i], r[i | j], ((i & k2) == 0) ? D : !D);
        }
      }
    }
#pragma unroll
    for (int q = 0; q < 8; ++q) {
      S4[sw4(row, (chunk << 3) + q)] =
          make_float4(r[q * 4 + 0], r[q * 4 + 1], r[q * 4 + 2], r[q * 4 + 3]);
    }
  }
  __syncthreads();

  for (int k = 64; k <= NMAPS; k <<= 1) {
    for (int j = k >> 1; j >= 32; j >>= 1) {
      const int j4 = j >> 2;
      const int kq = k >> 2;
#pragma unroll
      for (int q = 0; q < 8; ++q) {
        const int g = tid + (q << 8);
        const int row = g >> 7;
        const int v = g & 127;
        const int i4 = ((v & ~(j4 - 1)) << 1) | (v & (j4 - 1));
        const bool desc = ((i4 & kq) == 0);
        const int ia = sw4(row, i4);
        const int ib = sw4(row, i4 + j4);
        float4 va = S4[ia];
        float4 vb = S4[ib];
        float4 lo, hi;
        lo.x = fminf(va.x, vb.x); hi.x = fmaxf(va.x, vb.x);
        lo.y = fminf(va.y, vb.y); hi.y = fmaxf(va.y, vb.y);
        lo.z = fminf(va.z, vb.z); hi.z = fmaxf(va.z, vb.z);
        lo.w = fminf(va.w, vb.w); hi.w = fmaxf(va.w, vb.w);
        S4[ia] = desc ? hi : lo;
        S4[ib] = desc ? lo : hi;
      }
      __syncthreads();
    }
#pragma unroll
    for (int c = 0; c < 2; ++c) {
      const int cid = tid + (c << 8);
      const int row = cid >> 5;
      const int chunk = cid & 31;
      const bool D = (((chunk << 5) & k) == 0);
      float r[32];
#pragma unroll
      for (int q = 0; q < 8; ++q) {
        float4 t = S4[sw4(row, (chunk << 3) + q)];
        r[q * 4 + 0] = t.x; r[q * 4 + 1] = t.y; r[q * 4 + 2] = t.z; r[q * 4 + 3] = t.w;
      }
#pragma unroll
      for (int j = 16; j > 0; j >>= 1) {
#pragma unroll
        for (int i = 0; i < 32; ++i) {
          if ((i & j) == 0) ce(r[i], r[i | j], D);
        }
      }
#pragma unroll
      for (int q = 0; q < 8; ++q) {
        S4[sw4(row, (chunk << 3) + q)] =
            make_float4(r[q * 4 + 0], r[q * 4 + 1], r[q * 4 + 2], r[q * 4 + 3]);
      }
    }
    __syncthreads();
  }

  const int p = tid;
  const int rank = (int)rint(1.0 + (double)p * (1022.0 / 255.0));
#pragma unroll
  for (int m = 0; m < TM; ++m) {
    out[((size_t)(b * NMAPS + m0 + m) << 8) + p] = lds[sw4(m, rank >> 2) * 4 + (rank & 3)];
  }
}

extern "C" void kernel_launch(void* const* d_in, const int* in_sizes, int n_in,
                              void* d_out, int out_size, void* d_ws, size_t ws_size,
                              hipStream_t stream) {
  const float* x = reinterpret_cast<const float*>(d_in[0]);
  float* out = reinterpret_cast<float*>(d_out);
  const int nelem = in_sizes[0];
  const int B = nelem / (NMAPS * FDIM);  // 32
  const size_t need_split = (size_t)nelem * 2 + (size_t)B * NMAPS * NMAPS * 2;  // 96 MB
  if (ws_size >= need_split) {
    short* xw = reinterpret_cast<short*>(d_ws);
    unsigned* corrW = reinterpret_cast<unsigned*>((char*)d_ws + (size_t)nelem * 2);
    const int n8 = nelem / 8;
    hipLaunchKernelGGL(cvt_bf16_kernel, dim3((n8 + 255) / 256), dim3(256), 0, stream, x, xw, n8);
    hipLaunchKernelGGL(corr_gemm_tiled, dim3(32 * B), dim3(512), 0, stream, xw, corrW);
    hipLaunchKernelGGL(sort_rows_kernel, dim3(B * NMAPS / 8), dim3(256), 0, stream, corrW, out);
  } else if (ws_size >= (size_t)nelem * 2) {
    short* xw = reinterpret_cast<short*>(d_ws);
    const int n8 = nelem / 8;
    hipLaunchKernelGGL(cvt_bf16_kernel, dim3((n8 + 255) / 256), dim3(256), 0, stream, x, xw, n8);
    hipLaunchKernelGGL(selfcorr_mfma_kernel, dim3(NMAPS / TM, B), dim3(NT), 0, stream, xw, out);
  } else {
    hipLaunchKernelGGL(selfcorr_pool_kernel, dim3(NMAPS / TM, B), dim3(NT), 0, stream, x, out);
  }
}

// Round 13
// 154.515 us; speedup vs baseline: 1.0587x; 1.0587x over previous
//
#include <hip/hip_runtime.h>

// SelfCorrelationPercPooling: x (32,32,32,512) f32 ->
//   corr[b] = X·Xᵀ/512 (1024x1024), per-row descending sort, gather 256 ranks.
// v13 = v11 (best GEMM config: 1 A-tile, 32KB LDS, 2048 blocks, XCD swizzle)
//   with a COUNTED-VMCNT 2-barrier K-loop (T3/T4): the __syncthreads vmcnt(0)
//   drain was serializing staging latency against compute each of 16 K-steps.
//   Schedule: barA -> STAGE(next) -> vmcnt(2) -> barB -> read+MFMA (race-analyzed).
// Pipeline: cvt(bf16) -> corr_gemm_tiled (128-run epilogue) -> sort_rows -> out.
// Fallbacks: ws>=32MB -> v5 fused kernel; else v1 fp32 kernel.

#define NMAPS 1024
#define FDIM 512
#define TM 16
#define NT 256

typedef __attribute__((ext_vector_type(8))) short short8_t;  // bf16x8 MFMA frag
typedef __attribute__((ext_vector_type(4))) float f32x4;
typedef _Float16 h2 __attribute__((ext_vector_type(2)));     // packed fp16 pair

#define SELD 0x03020504u  // perm selector: (mx.lo16, mn.hi16) = desc pair
#define SELA 0x07060100u  // perm selector: (mn.lo16, mx.hi16) = asc pair

__device__ __forceinline__ h2 h2min(h2 a, h2 b) { return __builtin_elementwise_min(a, b); }
__device__ __forceinline__ h2 h2max(h2 a, h2 b) { return __builtin_elementwise_max(a, b); }

__device__ __forceinline__ unsigned h2u(h2 x) { union { h2 h; unsigned u; } t; t.h = x; return t.u; }
__device__ __forceinline__ h2 u2h(unsigned x) { union { h2 h; unsigned u; } t; t.u = x; return t.h; }

__device__ __forceinline__ h2 h2swap(h2 v) {
  unsigned u = h2u(v);
  return u2h((u >> 16) | (u << 16));
}

__device__ __forceinline__ h2 h2shfl_xor(h2 v, int m) {
  union { h2 h; int i; } u;
  u.h = v;
  u.i = __shfl_xor(u.i, m, 64);
  return u.h;
}

// packed word-pair CE, runtime direction
__device__ __forceinline__ void ce_pair(h2& a, h2& b, bool d) {
  h2 mn = h2min(a, b), mx = h2max(a, b);
  a = d ? mx : mn;
  b = d ? mn : mx;
}

// within-word CE (element stride 1) via perm selector (sel = SELD or SELA)
__device__ __forceinline__ h2 ce1(h2 w, unsigned sel) {
  h2 s = h2swap(w);
  h2 mn = h2min(w, s), mx = h2max(w, s);
#if __has_builtin(__builtin_amdgcn_perm)
  return u2h(__builtin_amdgcn_perm(h2u(mx), h2u(mn), sel));
#else
  h2 rd; rd[0] = mx[0]; rd[1] = mn[1];
  h2 ra; ra[0] = mn[0]; ra[1] = mx[1];
  return (sel == SELD) ? rd : ra;
#endif
}

// intra-lane merge of a 16-run (levels j=8,4,2,1), uniform direction d
__device__ __forceinline__ void intra_merge16(h2 w[8], bool d, unsigned sel) {
  ce_pair(w[0], w[4], d); ce_pair(w[1], w[5], d); ce_pair(w[2], w[6], d); ce_pair(w[3], w[7], d);
  ce_pair(w[0], w[2], d); ce_pair(w[1], w[3], d); ce_pair(w[4], w[6], d); ce_pair(w[5], w[7], d);
  ce_pair(w[0], w[1], d); ce_pair(w[2], w[3], d); ce_pair(w[4], w[5], d); ce_pair(w[6], w[7], d);
#pragma unroll
  for (int u = 0; u < 8; ++u) w[u] = ce1(w[u], sel);
}

// full bitonic sort of 16 in-lane elements, overall direction d  [verified v8/v9]
__device__ __forceinline__ void sort16(h2 w[8], bool d, unsigned sd, unsigned si) {
  w[0] = ce1(w[0], sd); w[1] = ce1(w[1], si); w[2] = ce1(w[2], sd); w[3] = ce1(w[3], si);
  w[4] = ce1(w[4], sd); w[5] = ce1(w[5], si); w[6] = ce1(w[6], sd); w[7] = ce1(w[7], si);
  ce_pair(w[0], w[1], d); ce_pair(w[2], w[3], !d); ce_pair(w[4], w[5], d); ce_pair(w[6], w[7], !d);
  w[0] = ce1(w[0], sd); w[1] = ce1(w[1], sd); w[2] = ce1(w[2], si); w[3] = ce1(w[3], si);
  w[4] = ce1(w[4], sd); w[5] = ce1(w[5], sd); w[6] = ce1(w[6], si); w[7] = ce1(w[7], si);
  ce_pair(w[0], w[2], d); ce_pair(w[1], w[3], d); ce_pair(w[4], w[6], !d); ce_pair(w[5], w[7], !d);
  ce_pair(w[0], w[1], d); ce_pair(w[2], w[3], d); ce_pair(w[4], w[5], !d); ce_pair(w[6], w[7], !d);
  w[0] = ce1(w[0], sd); w[1] = ce1(w[1], sd); w[2] = ce1(w[2], sd); w[3] = ce1(w[3], sd);
  w[4] = ce1(w[4], si); w[5] = ce1(w[5], si); w[6] = ce1(w[6], si); w[7] = ce1(w[7], si);
  intra_merge16(w, d, sd);
}

// in-lane bitonic merge of 32 elements (16 words), uniform direction d
__device__ __forceinline__ void merge32(h2 w[16], bool d) {
  const unsigned sel = d ? SELD : SELA;
#pragma unroll
  for (int u = 0; u < 8; ++u) ce_pair(w[u], w[u + 8], d);          // j=16
#pragma unroll
  for (int u = 0; u < 16; ++u)
    if ((u & 4) == 0) ce_pair(w[u], w[u | 4], d);                  // j=8
#pragma unroll
  for (int u = 0; u < 16; ++u)
    if ((u & 2) == 0) ce_pair(w[u], w[u | 2], d);                  // j=4
#pragma unroll
  for (int u = 0; u < 16; ++u)
    if ((u & 1) == 0) ce_pair(w[u], w[u | 1], d);                  // j=2
#pragma unroll
  for (int u = 0; u < 16; ++u) w[u] = ce1(w[u], sel);              // j=1
}

// cross-lane CE over N words (shuffle mask m), uniform keepmax
template<int N>
__device__ __forceinline__ void cross_ceN(h2* w, int m, bool keepmax) {
#pragma unroll
  for (int u = 0; u < N; ++u) {
    h2 p = h2shfl_xor(w[u], m);
    h2 mn = h2min(w[u], p), mx = h2max(w[u], p);
    w[u] = keepmax ? mx : mn;
  }
}
__device__ __forceinline__ void cross_ce(h2 w[8], int m, bool keepmax) {
  cross_ceN<8>(w, m, keepmax);
}

// One bitonic stage (block size K) on 1024 elements held as 8 h2/lane.
// Element i = lane*16 + 2*u + h. desc = ((i & K) == 0). [verified v5/v6/v7]
template<int K>
__device__ __forceinline__ void bitonic_stage(h2 w8[8], int lane) {
  const bool laneDesc = (K >= 16) ? ((lane & (K >> 4)) == 0) : true;
#pragma unroll
  for (int j = 512; j >= 16; j >>= 1) {
    if (j > (K >> 1)) continue;
    const int m = j >> 4;
    const bool keepmax = (((lane & m) == 0) == laneDesc);
#pragma unroll
    for (int u = 0; u < 8; ++u) {
      h2 p = h2shfl_xor(w8[u], m);
      h2 mn = h2min(w8[u], p), mx = h2max(w8[u], p);
      w8[u] = keepmax ? mx : mn;
    }
  }
#pragma unroll
  for (int j = 8; j >= 2; j >>= 1) {
    if (j > (K >> 1)) continue;
    const int jw = j >> 1;
#pragma unroll
    for (int u = 0; u < 8; ++u) {
      if ((u & jw) == 0) {
        const int v = u | jw;
        const bool desc = (K <= 8) ? (((2 * u) & K) == 0) : laneDesc;
        h2 mn = h2min(w8[u], w8[v]), mx = h2max(w8[u], w8[v]);
        w8[u] = desc ? mx : mn;
        w8[v] = desc ? mn : mx;
      }
    }
  }
#pragma unroll
  for (int u = 0; u < 8; ++u) {
    const bool desc = (K <= 8) ? (((2 * u) & K) == 0) : laneDesc;
    h2 s = h2swap(w8[u]);
    h2 mn = h2min(w8[u], s), mx = h2max(w8[u], s);
    h2 rd = (h2){mx[0], mn[1]};
    h2 ra = (h2){mn[0], mx[1]};
    w8[u] = desc ? rd : ra;
  }
}

// tail stage (K >= 128 only), TWO independent rows interleaved for ILP
template<int K>
__device__ __forceinline__ void bitonic_stage_tail2(h2 A[8], h2 B[8], int lane) {
  const bool laneDesc = ((lane & (K >> 4)) == 0);
#pragma unroll
  for (int j = 512; j >= 16; j >>= 1) {
    if (j > (K >> 1)) continue;
    const int m = j >> 4;
    const bool km = (((lane & m) == 0) == laneDesc);
    cross_ce(A, m, km);
    cross_ce(B, m, km);
  }
  const unsigned sel = laneDesc ? SELD : SELA;
  intra_merge16(A, laneDesc, sel);
  intra_merge16(B, laneDesc, sel);
}

__device__ __forceinline__ void run_bitonic(h2 w8[8], int lane) {  // full (fallbacks)
  bitonic_stage<2>(w8, lane);
  bitonic_stage<4>(w8, lane);
  bitonic_stage<8>(w8, lane);
  bitonic_stage<16>(w8, lane);
  bitonic_stage<32>(w8, lane);
  bitonic_stage<64>(w8, lane);
  bitonic_stage<128>(w8, lane);
  bitonic_stage<256>(w8, lane);
  bitonic_stage<512>(w8, lane);
  bitonic_stage<1024>(w8, lane);
}

// ---------------- fp32 -> bf16 (RNE) conversion pre-pass ----------------
__global__ __launch_bounds__(256) void cvt_bf16_kernel(const float* __restrict__ x,
                                                       short* __restrict__ xw, int n8) {
  int i = blockIdx.x * 256 + threadIdx.x;
  if (i >= n8) return;
  const float4* x4 = reinterpret_cast<const float4*>(x);
  float4 a = x4[i * 2], c = x4[i * 2 + 1];
  float f[8] = {a.x, a.y, a.z, a.w, c.x, c.y, c.z, c.w};
  union { short8_t v; short s[8]; } o;
#pragma unroll
  for (int j = 0; j < 8; ++j) {
    unsigned u = __float_as_uint(f[j]);
    u += 0x7fffu + ((u >> 16) & 1u);  // RNE (no NaN in data)
    o.s[j] = (short)(u >> 16);
  }
  reinterpret_cast<short8_t*>(xw)[i] = o.v;
}

// ---------------- kernel 2: TILED MFMA GEMM, counted-vmcnt double buffer ----------------
// C-tile 128x128/block (v11 config). BK=32; staging swizzle s^=(r>>1)&3 (verified).
// K-loop: barA -> STAGE(next) -> vmcnt(2) -> barB -> ds_read+MFMA.
//   barA: all waves' reads of the buffer being overwritten completed (MFMA-forced lgkm).
//   vmcnt(2): own cur-loads landed (2 newer loads stay in flight -- never drain to 0).
//   barB: everyone's cur-loads landed -> safe to ds_read.
// Epilogue: verified 128-run network (v10). UNSCALED fp16 -> ws.
__global__ __launch_bounds__(512) void corr_gemm_tiled(const short* __restrict__ xw,
                                                       unsigned* __restrict__ corrW) {
  __shared__ short Asm[2][128 * 32];  // 2 x 8 KB
  __shared__ short Bsm[2][128 * 32];  // 2 x 8 KB
  const int tid = threadIdx.x;
  int b, tile;
  if (gridDim.x == 2048) {
    const int bid = blockIdx.x;
    const int xcd = bid & 7;       // dispatch round-robins across 8 XCDs
    const int j = bid >> 3;        // 0..255
    b = (j >> 6) * 8 + xcd;        // 4 batches per XCD -> L2-resident panels
    tile = j & 63;
  } else {
    b = blockIdx.x >> 6;
    tile = blockIdx.x & 63;
  }
  const int it = tile >> 3, jt = tile & 7;
  const int i0 = it * 128, j0 = jt * 128;
  const int lane = tid & 63;
  const int w = tid >> 6;     // wave 0..7
  const int lr = lane & 15;
  const int kg = lane >> 4;   // 0..3
  const short* Xb = xw + (size_t)b * NMAPS * FDIM;

  // staging: one 16B chunk per thread per matrix (512 chunks = full 128x32 tile)
  const int sr = tid >> 2;
  const int ss = (tid & 3) ^ ((sr >> 1) & 3);  // pre-swizzled source chunk
  const int srcOff = sr * FDIM + ss * 8;
  const int dstOff = tid * 8;                  // shorts

  // read offsets (short units)
  const int rowa = w * 16 + lr;
  const int aOff = rowa * 32 + (kg ^ ((rowa >> 1) & 3)) * 8;
  int bOff[8];
#pragma unroll
  for (int fn = 0; fn < 8; ++fn) {
    const int rowb = fn * 16 + lr;
    bOff[fn] = rowb * 32 + (kg ^ ((rowb >> 1) & 3)) * 8;
  }

  f32x4 acc[8];
#pragma unroll
  for (int fn = 0; fn < 8; ++fn) acc[fn] = (f32x4){0.f, 0.f, 0.f, 0.f};

#define STAGE(buf, kt)                                                                \
  {                                                                                   \
    const short* gA = Xb + (size_t)i0 * FDIM + srcOff + (kt) * 32;                    \
    const short* gB = Xb + (size_t)j0 * FDIM + srcOff + (kt) * 32;                    \
    __builtin_amdgcn_global_load_lds(                                                 \
        (const __attribute__((address_space(1))) unsigned*)gA,                        \
        (__attribute__((address_space(3))) unsigned*)(Asm[buf] + dstOff), 16, 0, 0);  \
    __builtin_amdgcn_global_load_lds(                                                 \
        (const __attribute__((address_space(1))) unsigned*)gB,                        \
        (__attribute__((address_space(3))) unsigned*)(Bsm[buf] + dstOff), 16, 0, 0);  \
  }
#define SBAR() __builtin_amdgcn_sched_barrier(0)
#define BARRIER()                      \
  {                                    \
    SBAR();                            \
    __builtin_amdgcn_s_barrier();      \
    SBAR();                            \
  }

  STAGE(0, 0);

  for (int kt = 0; kt < 16; ++kt) {
    const int cur = kt & 1;
    BARRIER();  // A: prev iter's readers of cur^1 done (lgkm forced by their MFMAs)
    if (kt < 15) {
      STAGE(cur ^ 1, kt + 1);  // issue next tile into the buffer freed by barrier A
      SBAR();
      asm volatile("s_waitcnt vmcnt(2)" ::: "memory");  // own cur-loads landed
    } else {
      SBAR();
      asm volatile("s_waitcnt vmcnt(0)" ::: "memory");
    }
    BARRIER();  // B: ALL waves' cur-loads landed -> safe to read

    short8_t a = *reinterpret_cast<const short8_t*>(Asm[cur] + aOff);
    short8_t bf[8];
#pragma unroll
    for (int fn = 0; fn < 8; ++fn)
      bf[fn] = *reinterpret_cast<const short8_t*>(Bsm[cur] + bOff[fn]);
#pragma unroll
    for (int fn = 0; fn < 8; ++fn)
      acc[fn] = __builtin_amdgcn_mfma_f32_16x16x32_bf16(bf[fn], a, acc[fn], 0, 0, 0);
  }
#undef STAGE
#undef BARRIER
#undef SBAR

  // ---- epilogue: lane's 32 values (row i0+w*16+lr, cols j0+{fn*16+kg*4+reg}) ->
  //      sorted 128-run. Canonical dirs: desc=((i&K)==0); i bit5..6 = kg bits,
  //      i bit7 = jt&1. UNSCALED (scale deferred to scatter).  [verified v10]
  {
    const bool D128 = ((jt & 1) == 0);
    const bool d64 = ((kg & 2) == 0);
    const bool d32 = ((kg & 1) == 0);
    h2 W[16];
#pragma unroll
    for (int fn = 0; fn < 8; ++fn) {
      W[2 * fn] = (h2){(_Float16)acc[fn][0], (_Float16)acc[fn][1]};
      W[2 * fn + 1] = (h2){(_Float16)acc[fn][2], (_Float16)acc[fn][3]};
    }
    sort16(W, true, SELD, SELA);
    sort16(W + 8, false, SELA, SELD);
    merge32(W, d32);
    cross_ceN<16>(W, 16, d32 == d64);
    merge32(W, d64);
    cross_ceN<16>(W, 32, d64 == D128);
    cross_ceN<16>(W, 16, d32 == D128);
    merge32(W, D128);
    const size_t roww = ((size_t)b * NMAPS + i0 + w * 16 + lr) * 512;
    const int wq = (j0 >> 1) + kg * 16;
    union { h2 h[4]; uint4 u; } s0, s1, s2, s3;
#pragma unroll
    for (int q = 0; q < 4; ++q) { s0.h[q] = W[q]; s1.h[q] = W[4 + q]; s2.h[q] = W[8 + q]; s3.h[q] = W[12 + q]; }
    *reinterpret_cast<uint4*>(corrW + roww + wq) = s0.u;
    *reinterpret_cast<uint4*>(corrW + roww + wq + 4) = s1.u;
    *reinterpret_cast<uint4*>(corrW + roww + wq + 8) = s2.u;
    *reinterpret_cast<uint4*>(corrW + roww + wq + 12) = s3.u;
  }
}

// ---------------- kernel 3: tail sort (K=256..1024), TWO rows per wave + scatter ----------------
__global__ __launch_bounds__(256) void sort_rows_kernel(const unsigned* __restrict__ corrW,
                                                        float* __restrict__ out) {
  const int tid = threadIdx.x;
  const int lane = tid & 63;
  const int rA = blockIdx.x * 8 + (tid >> 6) * 2;  // wave handles rows rA, rA+1
  const int rB = rA + 1;
  const uint4* pa = reinterpret_cast<const uint4*>(corrW + (size_t)rA * 512);
  const uint4* pb = reinterpret_cast<const uint4*>(corrW + (size_t)rB * 512);

  h2 A[8], B[8];
  {
    union { uint4 u; h2 h[4]; } t0, t1;
    t0.u = pa[lane * 2]; t1.u = pa[lane * 2 + 1];
    A[0] = t0.h[0]; A[1] = t0.h[1]; A[2] = t0.h[2]; A[3] = t0.h[3];
    A[4] = t1.h[0]; A[5] = t1.h[1]; A[6] = t1.h[2]; A[7] = t1.h[3];
    t0.u = pb[lane * 2]; t1.u = pb[lane * 2 + 1];
    B[0] = t0.h[0]; B[1] = t0.h[1]; B[2] = t0.h[2]; B[3] = t0.h[3];
    B[4] = t1.h[0]; B[5] = t1.h[1]; B[6] = t1.h[2]; B[7] = t1.h[3];
  }

  // input: 128-runs sorted, desc iff (c&128)==0 -> start at K=256
  bitonic_stage_tail2<256>(A, B, lane);
  bitonic_stage_tail2<512>(A, B, lane);
  bitonic_stage_tail2<1024>(A, B, lane);

  float* oa = out + (size_t)rA * 256;
  float* ob = out + (size_t)rB * 256;
#pragma unroll
  for (int u = 0; u < 8; ++u) {
#pragma unroll
    for (int hh = 0; hh < 2; ++hh) {
      const int i = lane * 16 + 2 * u + hh;
      const int p = (int)rint((double)(i - 1) * (255.0 / 1022.0));
      const int rk = (int)rint(1.0 + (double)p * (1022.0 / 255.0));
      if (rk == i) {
        oa[p] = (float)A[u][hh] * (1.f / FDIM);  // deferred scale
        ob[p] = (float)B[u][hh] * (1.f / FDIM);
      }
    }
  }
}

// ---------------- v5 fused fallback (ws >= 32MB but < 96MB) ----------------
__global__ __launch_bounds__(NT) void selfcorr_mfma_kernel(const short* __restrict__ xw,
                                                           float* __restrict__ out) {
  __shared__ alignas(16) h2 SH[TM * 512];  // 32 KB
  const int tid = threadIdx.x;
  const int b = blockIdx.y;
  const int m0 = blockIdx.x * TM;
  const int lane = tid & 63;
  const int wid = tid >> 6;
  const int lr = lane & 15;
  const int kg = lane >> 4;
  const int wc = wid * 256;
  const short* Xb = xw + (size_t)b * NMAPS * FDIM;

  f32x4 acc[16];
#pragma unroll
  for (int t = 0; t < 16; ++t) acc[t] = (f32x4){0.f, 0.f, 0.f, 0.f};

  for (int kk = 0; kk < 16; ++kk) {
    const short8_t* base = reinterpret_cast<const short8_t*>(Xb + kk * 32 + kg * 8);
    short8_t afrag = base[(size_t)(m0 + lr) * 64];
    short8_t bfrag[16];
#pragma unroll
    for (int t = 0; t < 16; ++t) bfrag[t] = base[(size_t)(wc + t * 16 + lr) * 64];
#pragma unroll
    for (int t = 0; t < 16; ++t)
      acc[t] = __builtin_amdgcn_mfma_f32_16x16x32_bf16(bfrag[t], afrag, acc[t], 0, 0, 0);
  }

  {
    const int xorv = (lr & 7) << 2;
#pragma unroll
    for (int t = 0; t < 16; ++t) {
      h2 lo = (h2){(_Float16)(acc[t][0] * (1.f / FDIM)), (_Float16)(acc[t][1] * (1.f / FDIM))};
      h2 hi = (h2){(_Float16)(acc[t][2] * (1.f / FDIM)), (_Float16)(acc[t][3] * (1.f / FDIM))};
      const int W = (wc >> 1) + t * 8 + kg * 2;
      const int phys = lr * 512 + (W ^ xorv);
      union { h2 h[2]; uint2 u; } pk;
      pk.h[0] = lo; pk.h[1] = hi;
      *reinterpret_cast<uint2*>(&SH[phys]) = pk.u;
    }
  }
  __syncthreads();

  const int rowbase = wid * 4;
  for (int rr = rowbase; rr < rowbase + 4; ++rr) {
    const int rx = (rr & 7) << 2;
    h2 w8[8];
#pragma unroll
    for (int q = 0; q < 2; ++q) {
      const int p4 = rr * 512 + ((lane * 8 + q * 4) ^ rx);
      union { uint4 u; h2 h[4]; } un;
      un.u = *reinterpret_cast<const uint4*>(&SH[p4]);
      w8[q * 4 + 0] = un.h[0]; w8[q * 4 + 1] = un.h[1];
      w8[q * 4 + 2] = un.h[2]; w8[q * 4 + 3] = un.h[3];
    }
    run_bitonic(w8, lane);
#pragma unroll
    for (int q = 0; q < 2; ++q) {
      const int p4 = rr * 512 + ((lane * 8 + q * 4) ^ rx);
      union { uint4 u; h2 h[4]; } un;
      un.h[0] = w8[q * 4 + 0]; un.h[1] = w8[q * 4 + 1];
      un.h[2] = w8[q * 4 + 2]; un.h[3] = w8[q * 4 + 3];
      *reinterpret_cast<uint4*>(&SH[p4]) = un.u;
    }
  }
  __builtin_amdgcn_wave_barrier();

#pragma unroll
  for (int i = 0; i < 16; ++i) {
    const int rr = rowbase + (i >> 2);
    const int p = lane + ((i & 3) << 6);
    const int rank = (int)rint(1.0 + (double)p * (1022.0 / 255.0));
    const int Wr = (rank >> 1) ^ ((rr & 7) << 2);
    h2 hv = SH[rr * 512 + Wr];
    out[((size_t)(b * NMAPS + m0 + rr) << 8) + p] = (float)hv[rank & 1];
  }
}

// ---------------- v1 fp32 fallback (ws too small) ----------------
__device__ __forceinline__ int sw4(int row, int c4) {
  return (row << 8) | (c4 ^ ((c4 >> 3) & 7));
}
__device__ __forceinline__ void ce(float& a, float& b, bool desc) {
  float mn = fminf(a, b);
  float mx = fmaxf(a, b);
  a = desc ? mx : mn;
  b = desc ? mn : mx;
}

__global__ __launch_bounds__(NT) void selfcorr_pool_kernel(const float* __restrict__ x,
                                                           float* __restrict__ out) {
  __shared__ float lds[TM * NMAPS];
  float4* S4 = reinterpret_cast<float4*>(lds);
  const int tid = threadIdx.x;
  const int b = blockIdx.y;
  const int m0 = blockIdx.x * TM;
  const float4* Xb = reinterpret_cast<const float4*>(x) + (size_t)b * NMAPS * (FDIM / 4);

  float4* A4 = reinterpret_cast<float4*>(lds);
#pragma unroll
  for (int idx = tid; idx < TM * (FDIM / 4); idx += NT) {
    A4[idx] = Xb[(m0 + (idx >> 7)) * 128 + (idx & 127)];
  }
  __syncthreads();

  float acc[TM][4];
#pragma unroll
  for (int m = 0; m < TM; ++m)
#pragma unroll
    for (int j = 0; j < 4; ++j) acc[m][j] = 0.0f;

  float4 nb0 = Xb[(tid + 0) * 128];
  float4 nb1 = Xb[(tid + 256) * 128];
  float4 nb2 = Xb[(tid + 512) * 128];
  float4 nb3 = Xb[(tid + 768) * 128];
  for (int k4 = 0; k4 < 128; ++k4) {
    float4 b0 = nb0, b1 = nb1, b2 = nb2, b3 = nb3;
    const int kn = (k4 < 127) ? (k4 + 1) : 127;
    nb0 = Xb[(tid + 0) * 128 + kn];
    nb1 = Xb[(tid + 256) * 128 + kn];
    nb2 = Xb[(tid + 512) * 128 + kn];
    nb3 = Xb[(tid + 768) * 128 + kn];
#pragma unroll
    for (int m = 0; m < TM; ++m) {
      float4 a = A4[m * 128 + k4];
      acc[m][0] += a.x * b0.x + a.y * b0.y + a.z * b0.z + a.w * b0.w;
      acc[m][1] += a.x * b1.x + a.y * b1.y + a.z * b1.z + a.w * b1.w;
      acc[m][2] += a.x * b2.x + a.y * b2.y + a.z * b2.z + a.w * b2.w;
      acc[m][3] += a.x * b3.x + a.y * b3.y + a.z * b3.z + a.w * b3.w;
    }
  }
  __syncthreads();

#pragma unroll
  for (int m = 0; m < TM; ++m) {
#pragma unroll
    for (int j = 0; j < 4; ++j) {
      const int n = tid + (j << 8);
      lds[sw4(m, n >> 2) * 4 + (n & 3)] = acc[m][j] * (1.0f / FDIM);
    }
  }
  __syncthreads();

#pragma unroll
  for (int c = 0; c < 2; ++c) {
    const int cid = tid + (c << 8);
    const int row = cid >> 5;
    const int chunk = cid & 31;
    float r[32];
#pragma unroll
    for (int q = 0; q < 8; ++q) {
      float4 t = S4[sw4(row, (chunk << 3) + q)];
      r[q * 4 + 0] = t.x; r[q * 4 + 1] = t.y; r[q * 4 + 2] = t.z; r[q * 4 + 3] = t.w;
    }
    const bool D = ((chunk & 1) == 0);
#pragma unroll
    for (int k2 = 2; k2 <= 32; k2 <<= 1) {
#pragma unroll
      for (int j = k2 >> 1; j > 0; j >>= 1) {
#pragma unroll
        for (int i = 0; i < 32; ++i) {
          if ((i & j) == 0) ce(r[i], r[i | j], ((i & k2) == 0) ? D : !D);
        }
      }
    }
#pragma unroll
    for (int q = 0; q < 8; ++q) {
      S4[sw4(row, (chunk << 3) + q)] =
          make_float4(r[q * 4 + 0], r[q * 4 + 1], r[q * 4 + 2], r[q * 4 + 3]);
    }
  }
  __syncthreads();

  for (int k = 64; k <= NMAPS; k <<= 1) {
    for (int j = k >> 1; j >= 32; j >>= 1) {
      const int j4 = j >> 2;
      const int kq = k >> 2;
#pragma unroll
      for (int q = 0; q < 8; ++q) {
        const int g = tid + (q << 8);
        const int row = g >> 7;
        const int v = g & 127;
        const int i4 = ((v & ~(j4 - 1)) << 1) | (v & (j4 - 1));
        const bool desc = ((i4 & kq) == 0);
        const int ia = sw4(row, i4);
        const int ib = sw4(row, i4 + j4);
        float4 va = S4[ia];
        float4 vb = S4[ib];
        float4 lo, hi;
        lo.x = fminf(va.x, vb.x); hi.x = fmaxf(va.x, vb.x);
        lo.y = fminf(va.y, vb.y); hi.y = fmaxf(va.y, vb.y);
        lo.z = fminf(va.z, vb.z); hi.z = fmaxf(va.z, vb.z);
        lo.w = fminf(va.w, vb.w); hi.w = fmaxf(va.w, vb.w);
        S4[ia] = desc ? hi : lo;
        S4[ib] = desc ? lo : hi;
      }
      __syncthreads();
    }
#pragma unroll
    for (int c = 0; c < 2; ++c) {
      const int cid = tid + (c << 8);
      const int row = cid >> 5;
      const int chunk = cid & 31;
      const bool D = (((chunk << 5) & k) == 0);
      float r[32];
#pragma unroll
      for (int q = 0; q < 8; ++q) {
        float4 t = S4[sw4(row, (chunk << 3) + q)];
        r[q * 4 + 0] = t.x; r[q * 4 + 1] = t.y; r[q * 4 + 2] = t.z; r[q * 4 + 3] = t.w;
      }
#pragma unroll
      for (int j = 16; j > 0; j >>= 1) {
#pragma unroll
        for (int i = 0; i < 32; ++i) {
          if ((i & j) == 0) ce(r[i], r[i | j], D);
        }
      }
#pragma unroll
      for (int q = 0; q < 8; ++q) {
        S4[sw4(row, (chunk << 3) + q)] =
            make_float4(r[q * 4 + 0], r[q * 4 + 1], r[q * 4 + 2], r[q * 4 + 3]);
      }
    }
    __syncthreads();
  }

  const int p = tid;
  const int rank = (int)rint(1.0 + (double)p * (1022.0 / 255.0));
#pragma unroll
  for (int m = 0; m < TM; ++m) {
    out[((size_t)(b * NMAPS + m0 + m) << 8) + p] = lds[sw4(m, rank >> 2) * 4 + (rank & 3)];
  }
}

extern "C" void kernel_launch(void* const* d_in, const int* in_sizes, int n_in,
                              void* d_out, int out_size, void* d_ws, size_t ws_size,
                              hipStream_t stream) {
  const float* x = reinterpret_cast<const float*>(d_in[0]);
  float* out = reinterpret_cast<float*>(d_out);
  const int nelem = in_sizes[0];
  const int B = nelem / (NMAPS * FDIM);  // 32
  const size_t need_split = (size_t)nelem * 2 + (size_t)B * NMAPS * NMAPS * 2;  // 96 MB
  if (ws_size >= need_split) {
    short* xw = reinterpret_cast<short*>(d_ws);
    unsigned* corrW = reinterpret_cast<unsigned*>((char*)d_ws + (size_t)nelem * 2);
    const int n8 = nelem / 8;
    hipLaunchKernelGGL(cvt_bf16_kernel, dim3((n8 + 255) / 256), dim3(256), 0, stream, x, xw, n8);
    hipLaunchKernelGGL(corr_gemm_tiled, dim3(64 * B), dim3(512), 0, stream, xw, corrW);
    hipLaunchKernelGGL(sort_rows_kernel, dim3(B * NMAPS / 8), dim3(256), 0, stream, corrW, out);
  } else if (ws_size >= (size_t)nelem * 2) {
    short* xw = reinterpret_cast<short*>(d_ws);
    const int n8 = nelem / 8;
    hipLaunchKernelGGL(cvt_bf16_kernel, dim3((n8 + 255) / 256), dim3(256), 0, stream, x, xw, n8);
    hipLaunchKernelGGL(selfcorr_mfma_kernel, dim3(NMAPS / TM, B), dim3(NT), 0, stream, xw, out);
  } else {
    hipLaunchKernelGGL(selfcorr_pool_kernel, dim3(NMAPS / TM, B), dim3(NT), 0, stream, x, out);
  }
}

// Round 14
// 153.061 us; speedup vs baseline: 1.0687x; 1.0095x over previous
//
#include <hip/hip_runtime.h>

// SelfCorrelationPercPooling: x (32,32,32,512) f32 ->
//   corr[b] = X·Xᵀ/512 (1024x1024), per-row descending sort, gather 256 ranks.
// v14 = v13 with the GEMM moved to 32x32x16 MFMA (4 waves x 4 tiles, 256 thr):
//   reads-per-output halves (LDS-read issue was ~46us of 83.5), LDS stays 32KB.
//   Epilogue: full in-lane sort64 + one lane^32 cross + merge64 -> sorted
//   128-runs (same store convention; sort_rows unchanged). Counted-vmcnt loop
//   (v13, verified) with vmcnt(4) for the 4 loads per STAGE.
// Pipeline: cvt(bf16) -> corr_gemm_tiled -> sort_rows -> out.
// Fallbacks: ws>=32MB -> v5 fused kernel; else v1 fp32 kernel.

#define NMAPS 1024
#define FDIM 512
#define TM 16
#define NT 256

typedef __attribute__((ext_vector_type(8))) short short8_t;   // bf16x8 MFMA frag
typedef __attribute__((ext_vector_type(4))) float f32x4;
typedef __attribute__((ext_vector_type(16))) float f32x16;    // 32x32 accumulator
typedef _Float16 h2 __attribute__((ext_vector_type(2)));      // packed fp16 pair

#define SELD 0x03020504u  // perm selector: (mx.lo16, mn.hi16) = desc pair
#define SELA 0x07060100u  // perm selector: (mn.lo16, mx.hi16) = asc pair

__device__ __forceinline__ h2 h2min(h2 a, h2 b) { return __builtin_elementwise_min(a, b); }
__device__ __forceinline__ h2 h2max(h2 a, h2 b) { return __builtin_elementwise_max(a, b); }

__device__ __forceinline__ unsigned h2u(h2 x) { union { h2 h; unsigned u; } t; t.h = x; return t.u; }
__device__ __forceinline__ h2 u2h(unsigned x) { union { h2 h; unsigned u; } t; t.u = x; return t.h; }

__device__ __forceinline__ h2 h2swap(h2 v) {
  unsigned u = h2u(v);
  return u2h((u >> 16) | (u << 16));
}

__device__ __forceinline__ h2 h2shfl_xor(h2 v, int m) {
  union { h2 h; int i; } u;
  u.h = v;
  u.i = __shfl_xor(u.i, m, 64);
  return u.h;
}

// packed word-pair CE, runtime direction
__device__ __forceinline__ void ce_pair(h2& a, h2& b, bool d) {
  h2 mn = h2min(a, b), mx = h2max(a, b);
  a = d ? mx : mn;
  b = d ? mn : mx;
}

// within-word CE (element stride 1) via perm selector (sel = SELD or SELA)
__device__ __forceinline__ h2 ce1(h2 w, unsigned sel) {
  h2 s = h2swap(w);
  h2 mn = h2min(w, s), mx = h2max(w, s);
#if __has_builtin(__builtin_amdgcn_perm)
  return u2h(__builtin_amdgcn_perm(h2u(mx), h2u(mn), sel));
#else
  h2 rd; rd[0] = mx[0]; rd[1] = mn[1];
  h2 ra; ra[0] = mn[0]; ra[1] = mx[1];
  return (sel == SELD) ? rd : ra;
#endif
}

// intra-lane merge of a 16-run (levels j=8,4,2,1), uniform direction d
__device__ __forceinline__ void intra_merge16(h2 w[8], bool d, unsigned sel) {
  ce_pair(w[0], w[4], d); ce_pair(w[1], w[5], d); ce_pair(w[2], w[6], d); ce_pair(w[3], w[7], d);
  ce_pair(w[0], w[2], d); ce_pair(w[1], w[3], d); ce_pair(w[4], w[6], d); ce_pair(w[5], w[7], d);
  ce_pair(w[0], w[1], d); ce_pair(w[2], w[3], d); ce_pair(w[4], w[5], d); ce_pair(w[6], w[7], d);
#pragma unroll
  for (int u = 0; u < 8; ++u) w[u] = ce1(w[u], sel);
}

// full bitonic sort of 16 in-lane elements, overall direction d  [verified v8-v13]
__device__ __forceinline__ void sort16(h2 w[8], bool d, unsigned sd, unsigned si) {
  w[0] = ce1(w[0], sd); w[1] = ce1(w[1], si); w[2] = ce1(w[2], sd); w[3] = ce1(w[3], si);
  w[4] = ce1(w[4], sd); w[5] = ce1(w[5], si); w[6] = ce1(w[6], sd); w[7] = ce1(w[7], si);
  ce_pair(w[0], w[1], d); ce_pair(w[2], w[3], !d); ce_pair(w[4], w[5], d); ce_pair(w[6], w[7], !d);
  w[0] = ce1(w[0], sd); w[1] = ce1(w[1], sd); w[2] = ce1(w[2], si); w[3] = ce1(w[3], si);
  w[4] = ce1(w[4], sd); w[5] = ce1(w[5], sd); w[6] = ce1(w[6], si); w[7] = ce1(w[7], si);
  ce_pair(w[0], w[2], d); ce_pair(w[1], w[3], d); ce_pair(w[4], w[6], !d); ce_pair(w[5], w[7], !d);
  ce_pair(w[0], w[1], d); ce_pair(w[2], w[3], d); ce_pair(w[4], w[5], !d); ce_pair(w[6], w[7], !d);
  w[0] = ce1(w[0], sd); w[1] = ce1(w[1], sd); w[2] = ce1(w[2], sd); w[3] = ce1(w[3], sd);
  w[4] = ce1(w[4], si); w[5] = ce1(w[5], si); w[6] = ce1(w[6], si); w[7] = ce1(w[7], si);
  intra_merge16(w, d, sd);
}

// in-lane bitonic merge of 32 elements (16 words), uniform direction d
__device__ __forceinline__ void merge32(h2 w[16], bool d) {
  const unsigned sel = d ? SELD : SELA;
#pragma unroll
  for (int u = 0; u < 8; ++u) ce_pair(w[u], w[u + 8], d);          // j=16
#pragma unroll
  for (int u = 0; u < 16; ++u)
    if ((u & 4) == 0) ce_pair(w[u], w[u | 4], d);                  // j=8
#pragma unroll
  for (int u = 0; u < 16; ++u)
    if ((u & 2) == 0) ce_pair(w[u], w[u | 2], d);                  // j=4
#pragma unroll
  for (int u = 0; u < 16; ++u)
    if ((u & 1) == 0) ce_pair(w[u], w[u | 1], d);                  // j=2
#pragma unroll
  for (int u = 0; u < 16; ++u) w[u] = ce1(w[u], sel);              // j=1
}

// in-lane bitonic merge of 64 elements (32 words), uniform direction d
__device__ __forceinline__ void merge64(h2 w[32], bool d) {
  const unsigned sel = d ? SELD : SELA;
#pragma unroll
  for (int u = 0; u < 16; ++u) ce_pair(w[u], w[u + 16], d);        // j=32
#pragma unroll
  for (int u = 0; u < 32; ++u)
    if ((u & 8) == 0) ce_pair(w[u], w[u | 8], d);                  // j=16
#pragma unroll
  for (int u = 0; u < 32; ++u)
    if ((u & 4) == 0) ce_pair(w[u], w[u | 4], d);                  // j=8
#pragma unroll
  for (int u = 0; u < 32; ++u)
    if ((u & 2) == 0) ce_pair(w[u], w[u | 2], d);                  // j=4
#pragma unroll
  for (int u = 0; u < 32; ++u)
    if ((u & 1) == 0) ce_pair(w[u], w[u | 1], d);                  // j=2
#pragma unroll
  for (int u = 0; u < 32; ++u) w[u] = ce1(w[u], sel);              // j=1
}

// cross-lane CE over N words (shuffle mask m), uniform keepmax
template<int N>
__device__ __forceinline__ void cross_ceN(h2* w, int m, bool keepmax) {
#pragma unroll
  for (int u = 0; u < N; ++u) {
    h2 p = h2shfl_xor(w[u], m);
    h2 mn = h2min(w[u], p), mx = h2max(w[u], p);
    w[u] = keepmax ? mx : mn;
  }
}
__device__ __forceinline__ void cross_ce(h2 w[8], int m, bool keepmax) {
  cross_ceN<8>(w, m, keepmax);
}

// One bitonic stage (block size K) on 1024 elements held as 8 h2/lane.
// Element i = lane*16 + 2*u + h. desc = ((i & K) == 0). [verified v5/v6/v7]
template<int K>
__device__ __forceinline__ void bitonic_stage(h2 w8[8], int lane) {
  const bool laneDesc = (K >= 16) ? ((lane & (K >> 4)) == 0) : true;
#pragma unroll
  for (int j = 512; j >= 16; j >>= 1) {
    if (j > (K >> 1)) continue;
    const int m = j >> 4;
    const bool keepmax = (((lane & m) == 0) == laneDesc);
#pragma unroll
    for (int u = 0; u < 8; ++u) {
      h2 p = h2shfl_xor(w8[u], m);
      h2 mn = h2min(w8[u], p), mx = h2max(w8[u], p);
      w8[u] = keepmax ? mx : mn;
    }
  }
#pragma unroll
  for (int j = 8; j >= 2; j >>= 1) {
    if (j > (K >> 1)) continue;
    const int jw = j >> 1;
#pragma unroll
    for (int u = 0; u < 8; ++u) {
      if ((u & jw) == 0) {
        const int v = u | jw;
        const bool desc = (K <= 8) ? (((2 * u) & K) == 0) : laneDesc;
        h2 mn = h2min(w8[u], w8[v]), mx = h2max(w8[u], w8[v]);
        w8[u] = desc ? mx : mn;
        w8[v] = desc ? mn : mx;
      }
    }
  }
#pragma unroll
  for (int u = 0; u < 8; ++u) {
    const bool desc = (K <= 8) ? (((2 * u) & K) == 0) : laneDesc;
    h2 s = h2swap(w8[u]);
    h2 mn = h2min(w8[u], s), mx = h2max(w8[u], s);
    h2 rd = (h2){mx[0], mn[1]};
    h2 ra = (h2){mn[0], mx[1]};
    w8[u] = desc ? rd : ra;
  }
}

// tail stage (K >= 128 only), TWO independent rows interleaved for ILP
template<int K>
__device__ __forceinline__ void bitonic_stage_tail2(h2 A[8], h2 B[8], int lane) {
  const bool laneDesc = ((lane & (K >> 4)) == 0);
#pragma unroll
  for (int j = 512; j >= 16; j >>= 1) {
    if (j > (K >> 1)) continue;
    const int m = j >> 4;
    const bool km = (((lane & m) == 0) == laneDesc);
    cross_ce(A, m, km);
    cross_ce(B, m, km);
  }
  const unsigned sel = laneDesc ? SELD : SELA;
  intra_merge16(A, laneDesc, sel);
  intra_merge16(B, laneDesc, sel);
}

__device__ __forceinline__ void run_bitonic(h2 w8[8], int lane) {  // full (fallbacks)
  bitonic_stage<2>(w8, lane);
  bitonic_stage<4>(w8, lane);
  bitonic_stage<8>(w8, lane);
  bitonic_stage<16>(w8, lane);
  bitonic_stage<32>(w8, lane);
  bitonic_stage<64>(w8, lane);
  bitonic_stage<128>(w8, lane);
  bitonic_stage<256>(w8, lane);
  bitonic_stage<512>(w8, lane);
  bitonic_stage<1024>(w8, lane);
}

// ---------------- fp32 -> bf16 (RNE) conversion pre-pass ----------------
__global__ __launch_bounds__(256) void cvt_bf16_kernel(const float* __restrict__ x,
                                                       short* __restrict__ xw, int n8) {
  int i = blockIdx.x * 256 + threadIdx.x;
  if (i >= n8) return;
  const float4* x4 = reinterpret_cast<const float4*>(x);
  float4 a = x4[i * 2], c = x4[i * 2 + 1];
  float f[8] = {a.x, a.y, a.z, a.w, c.x, c.y, c.z, c.w};
  union { short8_t v; short s[8]; } o;
#pragma unroll
  for (int j = 0; j < 8; ++j) {
    unsigned u = __float_as_uint(f[j]);
    u += 0x7fffu + ((u >> 16) & 1u);  // RNE (no NaN in data)
    o.s[j] = (short)(u >> 16);
  }
  reinterpret_cast<short8_t*>(xw)[i] = o.v;
}

// ---------------- kernel 2: TILED 32x32x16 MFMA GEMM, counted-vmcnt dbuf ----------------
// 128x128 C-tile/block, 4 waves x 4 (32x32) tiles, BK=32 (2 K-steps of 16).
// Swapped operands: mfma(bfrag, afrag) -> lane holds corr row = lane&31; lane-pair
// (l, l^32) holds the full 128-col panel of that row. Epilogue: in-lane sort64
// (halves opposite) -> cross(32) -> merge64 = sorted 128-run, desc iff jt even.
// Staging swizzle s^=(r>>1)&3 + counted-vmcnt schedule (verified v13), 4 loads/STAGE.
__global__ __launch_bounds__(256) void corr_gemm_tiled(const short* __restrict__ xw,
                                                       unsigned* __restrict__ corrW) {
  __shared__ short Asm[2][128 * 32];  // 2 x 8 KB
  __shared__ short Bsm[2][128 * 32];  // 2 x 8 KB
  const int tid = threadIdx.x;
  int b, tile;
  if (gridDim.x == 2048) {
    const int bid = blockIdx.x;
    const int xcd = bid & 7;       // dispatch round-robins across 8 XCDs
    const int j = bid >> 3;        // 0..255
    b = (j >> 6) * 8 + xcd;        // 4 batches per XCD -> L2-resident panels
    tile = j & 63;
  } else {
    b = blockIdx.x >> 6;
    tile = blockIdx.x & 63;
  }
  const int it = tile >> 3, jt = tile & 7;
  const int i0 = it * 128, j0 = jt * 128;
  const int lane = tid & 63;
  const int w = tid >> 6;        // wave 0..3 (owns rows [i0+32w, +32))
  const int lr32 = lane & 31;    // operand row within 32-row group
  const int hi = lane >> 5;      // k-half / col-phase
  const short* Xb = xw + (size_t)b * NMAPS * FDIM;

  // staging: 2 chunk-slots per thread per matrix (512 chunks = 128x32 tile)
  int srcOff[2], dstOff[2];
  {
    const int idxs[2] = {tid, tid + 256};
#pragma unroll
    for (int rp = 0; rp < 2; ++rp) {
      const int r = idxs[rp] >> 2;
      const int s = (idxs[rp] & 3) ^ ((r >> 1) & 3);  // pre-swizzled source chunk
      srcOff[rp] = r * FDIM + s * 8;
      dstOff[rp] = idxs[rp] * 8;
    }
  }

  // read offsets (shorts): chunk = 2*ks + hi; addr = row*32 + (chunk ^ ((row>>1)&3))*8
  int aOff[2], bOff[4][2];
  {
    const int ra = w * 32 + lr32;
#pragma unroll
    for (int ks = 0; ks < 2; ++ks)
      aOff[ks] = ra * 32 + (((2 * ks + hi) ^ ((ra >> 1) & 3)) * 8);
#pragma unroll
    for (int tc = 0; tc < 4; ++tc) {
      const int rb = tc * 32 + lr32;
#pragma unroll
      for (int ks = 0; ks < 2; ++ks)
        bOff[tc][ks] = rb * 32 + (((2 * ks + hi) ^ ((rb >> 1) & 3)) * 8);
    }
  }

  f32x16 acc[4];
#pragma unroll
  for (int tc = 0; tc < 4; ++tc)
#pragma unroll
    for (int q = 0; q < 16; ++q) acc[tc][q] = 0.f;

#define STAGE(buf, kt)                                                                 \
  {                                                                                    \
    _Pragma("unroll") for (int rp = 0; rp < 2; ++rp) {                                 \
      const short* gA = Xb + (size_t)i0 * FDIM + srcOff[rp] + (kt) * 32;               \
      const short* gB = Xb + (size_t)j0 * FDIM + srcOff[rp] + (kt) * 32;               \
      __builtin_amdgcn_global_load_lds(                                                \
          (const __attribute__((address_space(1))) unsigned*)gA,                       \
          (__attribute__((address_space(3))) unsigned*)(Asm[buf] + dstOff[rp]), 16,    \
          0, 0);                                                                       \
      __builtin_amdgcn_global_load_lds(                                                \
          (const __attribute__((address_space(1))) unsigned*)gB,                       \
          (__attribute__((address_space(3))) unsigned*)(Bsm[buf] + dstOff[rp]), 16,    \
          0, 0);                                                                       \
    }                                                                                  \
  }
#define SBAR() __builtin_amdgcn_sched_barrier(0)
#define BARRIER()                      \
  {                                    \
    SBAR();                            \
    __builtin_amdgcn_s_barrier();      \
    SBAR();                            \
  }

  STAGE(0, 0);

  for (int kt = 0; kt < 16; ++kt) {
    const int cur = kt & 1;
    BARRIER();  // A: prev iter's readers of cur^1 done (lgkm forced by their MFMAs)
    if (kt < 15) {
      STAGE(cur ^ 1, kt + 1);  // 4 loads into the buffer freed by barrier A
      SBAR();
      asm volatile("s_waitcnt vmcnt(4)" ::: "memory");  // own cur-loads landed
    } else {
      SBAR();
      asm volatile("s_waitcnt vmcnt(0)" ::: "memory");
    }
    BARRIER();  // B: ALL waves' cur-loads landed -> safe to read

#pragma unroll
    for (int ks = 0; ks < 2; ++ks) {
      short8_t a = *reinterpret_cast<const short8_t*>(Asm[cur] + aOff[ks]);
      short8_t bf[4];
#pragma unroll
      for (int tc = 0; tc < 4; ++tc)
        bf[tc] = *reinterpret_cast<const short8_t*>(Bsm[cur] + bOff[tc][ks]);
#pragma unroll
      for (int tc = 0; tc < 4; ++tc)
        acc[tc] = __builtin_amdgcn_mfma_f32_32x32x16_bf16(bf[tc], a, acc[tc], 0, 0, 0);
    }
  }
#undef STAGE
#undef BARRIER
#undef SBAR

  // ---- epilogue: lane's 64 values (row i0+32w+lr32; 16 cols per tile x 4 tiles;
  //      lane-pair l/l^32 holds the FULL 128-col panel of the row) ->
  //      in-lane sort64 (dir: desc iff hi==0) -> stage128 -> sorted 128-run.
  //      desc iff jt even. UNSCALED (scale deferred to scatter).
  {
    const bool D = ((jt & 1) == 0);
    h2 W[32];
#pragma unroll
    for (int tc = 0; tc < 4; ++tc)
#pragma unroll
      for (int q = 0; q < 8; ++q)
        W[tc * 8 + q] = (h2){(_Float16)acc[tc][2 * q], (_Float16)acc[tc][2 * q + 1]};
    // sort64 in-lane: halves opposite, merge with dir (hi==0)
    sort16(W, true, SELD, SELA);
    sort16(W + 8, false, SELA, SELD);
    merge32(W, true);                    // W[0..15] sorted desc (32)
    sort16(W + 16, true, SELD, SELA);
    sort16(W + 24, false, SELA, SELD);
    merge32(W + 16, false);              // W[16..31] sorted asc (32)
    merge64(W, hi == 0);                 // stage 64: desc iff hi==0
    // stage 128
    cross_ceN<32>(W, 32, (hi == 0) == D);  // j=64 across lane^32
    merge64(W, D);                          // j=32..1 in-lane
    // store: lane covers 64 contiguous slots at panel offset hi*64
    const size_t roww = ((size_t)b * NMAPS + i0 + w * 32 + lr32) * 512;
    const int wq = (j0 >> 1) + hi * 32;
#pragma unroll
    for (int g = 0; g < 8; ++g) {
      union { h2 h[4]; uint4 u; } s;
#pragma unroll
      for (int q = 0; q < 4; ++q) s.h[q] = W[g * 4 + q];
      *reinterpret_cast<uint4*>(corrW + roww + wq + g * 4) = s.u;
    }
  }
}

// ---------------- kernel 3: tail sort (K=256..1024), TWO rows per wave + scatter ----------------
__global__ __launch_bounds__(256) void sort_rows_kernel(const unsigned* __restrict__ corrW,
                                                        float* __restrict__ out) {
  const int tid = threadIdx.x;
  const int lane = tid & 63;
  const int rA = blockIdx.x * 8 + (tid >> 6) * 2;  // wave handles rows rA, rA+1
  const int rB = rA + 1;
  const uint4* pa = reinterpret_cast<const uint4*>(corrW + (size_t)rA * 512);
  const uint4* pb = reinterpret_cast<const uint4*>(corrW + (size_t)rB * 512);

  h2 A[8], B[8];
  {
    union { uint4 u; h2 h[4]; } t0, t1;
    t0.u = pa[lane * 2]; t1.u = pa[lane * 2 + 1];
    A[0] = t0.h[0]; A[1] = t0.h[1]; A[2] = t0.h[2]; A[3] = t0.h[3];
    A[4] = t1.h[0]; A[5] = t1.h[1]; A[6] = t1.h[2]; A[7] = t1.h[3];
    t0.u = pb[lane * 2]; t1.u = pb[lane * 2 + 1];
    B[0] = t0.h[0]; B[1] = t0.h[1]; B[2] = t0.h[2]; B[3] = t0.h[3];
    B[4] = t1.h[0]; B[5] = t1.h[1]; B[6] = t1.h[2]; B[7] = t1.h[3];
  }

  // input: 128-runs sorted, desc iff (c&128)==0 -> start at K=256
  bitonic_stage_tail2<256>(A, B, lane);
  bitonic_stage_tail2<512>(A, B, lane);
  bitonic_stage_tail2<1024>(A, B, lane);

  float* oa = out + (size_t)rA * 256;
  float* ob = out + (size_t)rB * 256;
#pragma unroll
  for (int u = 0; u < 8; ++u) {
#pragma unroll
    for (int hh = 0; hh < 2; ++hh) {
      const int i = lane * 16 + 2 * u + hh;
      const int p = (int)rint((double)(i - 1) * (255.0 / 1022.0));
      const int rk = (int)rint(1.0 + (double)p * (1022.0 / 255.0));
      if (rk == i) {
        oa[p] = (float)A[u][hh] * (1.f / FDIM);  // deferred scale
        ob[p] = (float)B[u][hh] * (1.f / FDIM);
      }
    }
  }
}

// ---------------- v5 fused fallback (ws >= 32MB but < 96MB) ----------------
__global__ __launch_bounds__(NT) void selfcorr_mfma_kernel(const short* __restrict__ xw,
                                                           float* __restrict__ out) {
  __shared__ alignas(16) h2 SH[TM * 512];  // 32 KB
  const int tid = threadIdx.x;
  const int b = blockIdx.y;
  const int m0 = blockIdx.x * TM;
  const int lane = tid & 63;
  const int wid = tid >> 6;
  const int lr = lane & 15;
  const int kg = lane >> 4;
  const int wc = wid * 256;
  const short* Xb = xw + (size_t)b * NMAPS * FDIM;

  f32x4 acc[16];
#pragma unroll
  for (int t = 0; t < 16; ++t) acc[t] = (f32x4){0.f, 0.f, 0.f, 0.f};

  for (int kk = 0; kk < 16; ++kk) {
    const short8_t* base = reinterpret_cast<const short8_t*>(Xb + kk * 32 + kg * 8);
    short8_t afrag = base[(size_t)(m0 + lr) * 64];
    short8_t bfrag[16];
#pragma unroll
    for (int t = 0; t < 16; ++t) bfrag[t] = base[(size_t)(wc + t * 16 + lr) * 64];
#pragma unroll
    for (int t = 0; t < 16; ++t)
      acc[t] = __builtin_amdgcn_mfma_f32_16x16x32_bf16(bfrag[t], afrag, acc[t], 0, 0, 0);
  }

  {
    const int xorv = (lr & 7) << 2;
#pragma unroll
    for (int t = 0; t < 16; ++t) {
      h2 lo = (h2){(_Float16)(acc[t][0] * (1.f / FDIM)), (_Float16)(acc[t][1] * (1.f / FDIM))};
      h2 hi = (h2){(_Float16)(acc[t][2] * (1.f / FDIM)), (_Float16)(acc[t][3] * (1.f / FDIM))};
      const int W = (wc >> 1) + t * 8 + kg * 2;
      const int phys = lr * 512 + (W ^ xorv);
      union { h2 h[2]; uint2 u; } pk;
      pk.h[0] = lo; pk.h[1] = hi;
      *reinterpret_cast<uint2*>(&SH[phys]) = pk.u;
    }
  }
  __syncthreads();

  const int rowbase = wid * 4;
  for (int rr = rowbase; rr < rowbase + 4; ++rr) {
    const int rx = (rr & 7) << 2;
    h2 w8[8];
#pragma unroll
    for (int q = 0; q < 2; ++q) {
      const int p4 = rr * 512 + ((lane * 8 + q * 4) ^ rx);
      union { uint4 u; h2 h[4]; } un;
      un.u = *reinterpret_cast<const uint4*>(&SH[p4]);
      w8[q * 4 + 0] = un.h[0]; w8[q * 4 + 1] = un.h[1];
      w8[q * 4 + 2] = un.h[2]; w8[q * 4 + 3] = un.h[3];
    }
    run_bitonic(w8, lane);
#pragma unroll
    for (int q = 0; q < 2; ++q) {
      const int p4 = rr * 512 + ((lane * 8 + q * 4) ^ rx);
      union { uint4 u; h2 h[4]; } un;
      un.h[0] = w8[q * 4 + 0]; un.h[1] = w8[q * 4 + 1];
      un.h[2] = w8[q * 4 + 2]; un.h[3] = w8[q * 4 + 3];
      *reinterpret_cast<uint4*>(&SH[p4]) = un.u;
    }
  }
  __builtin_amdgcn_wave_barrier();

#pragma unroll
  for (int i = 0; i < 16; ++i) {
    const int rr = rowbase + (i >> 2);
    const int p = lane + ((i & 3) << 6);
    const int rank = (int)rint(1.0 + (double)p * (1022.0 / 255.0));
    const int Wr = (rank >> 1) ^ ((rr & 7) << 2);
    h2 hv = SH[rr * 512 + Wr];
    out[((size_t)(b * NMAPS + m0 + rr) << 8) + p] = (float)hv[rank & 1];
  }
}

// ---------------- v1 fp32 fallback (ws too small) ----------------
__device__ __forceinline__ int sw4(int row, int c4) {
  return (row << 8) | (c4 ^ ((c4 >> 3) & 7));
}
__device__ __forceinline__ void ce(float& a, float& b, bool desc) {
  float mn = fminf(a, b);
  float mx = fmaxf(a, b);
  a = desc ? mx : mn;
  b = desc ? mn : mx;
}

__global__ __launch_bounds__(NT) void selfcorr_pool_kernel(const float* __restrict__ x,
                                                           float* __restrict__ out) {
  __shared__ float lds[TM * NMAPS];
  float4* S4 = reinterpret_cast<float4*>(lds);
  const int tid = threadIdx.x;
  const int b = blockIdx.y;
  const int m0 = blockIdx.x * TM;
  const float4* Xb = reinterpret_cast<const float4*>(x) + (size_t)b * NMAPS * (FDIM / 4);

  float4* A4 = reinterpret_cast<float4*>(lds);
#pragma unroll
  for (int idx = tid; idx < TM * (FDIM / 4); idx += NT) {
    A4[idx] = Xb[(m0 + (idx >> 7)) * 128 + (idx & 127)];
  }
  __syncthreads();

  float acc[TM][4];
#pragma unroll
  for (int m = 0; m < TM; ++m)
#pragma unroll
    for (int j = 0; j < 4; ++j) acc[m][j] = 0.0f;

  float4 nb0 = Xb[(tid + 0) * 128];
  float4 nb1 = Xb[(tid + 256) * 128];
  float4 nb2 = Xb[(tid + 512) * 128];
  float4 nb3 = Xb[(tid + 768) * 128];
  for (int k4 = 0; k4 < 128; ++k4) {
    float4 b0 = nb0, b1 = nb1, b2 = nb2, b3 = nb3;
    const int kn = (k4 < 127) ? (k4 + 1) : 127;
    nb0 = Xb[(tid + 0) * 128 + kn];
    nb1 = Xb[(tid + 256) * 128 + kn];
    nb2 = Xb[(tid + 512) * 128 + kn];
    nb3 = Xb[(tid + 768) * 128 + kn];
#pragma unroll
    for (int m = 0; m < TM; ++m) {
      float4 a = A4[m * 128 + k4];
      acc[m][0] += a.x * b0.x + a.y * b0.y + a.z * b0.z + a.w * b0.w;
      acc[m][1] += a.x * b1.x + a.y * b1.y + a.z * b1.z + a.w * b1.w;
      acc[m][2] += a.x * b2.x + a.y * b2.y + a.z * b2.z + a.w * b2.w;
      acc[m][3] += a.x * b3.x + a.y * b3.y + a.z * b3.z + a.w * b3.w;
    }
  }
  __syncthreads();

#pragma unroll
  for (int m = 0; m < TM; ++m) {
#pragma unroll
    for (int j = 0; j < 4; ++j) {
      const int n = tid + (j << 8);
      lds[sw4(m, n >> 2) * 4 + (n & 3)] = acc[m][j] * (1.0f / FDIM);
    }
  }
  __syncthreads();

#pragma unroll
  for (int c = 0; c < 2; ++c) {
    const int cid = tid + (c << 8);
    const int row = cid >> 5;
    const int chunk = cid & 31;
    float r[32];
#pragma unroll
    for (int q = 0; q < 8; ++q) {
      float4 t = S4[sw4(row, (chunk << 3) + q)];
      r[q * 4 + 0] = t.x; r[q * 4 + 1] = t.y; r[q * 4 + 2] = t.z; r[q * 4 + 3] = t.w;
    }
    const bool D = ((chunk & 1) == 0);
#pragma unroll
    for (int k2 = 2; k2 <= 32; k2 <<= 1) {
#pragma unroll
      for (int j = k2 >> 1; j > 0; j >>= 1) {
#pragma unroll
        for (int i = 0; i < 32; ++i) {
          if ((i & j) == 0) ce(r[i], r[i | j], ((i & k2) == 0) ? D : !D);
        }
      }
    }
#pragma unroll
    for (int q = 0; q < 8; ++q) {
      S4[sw4(row, (chunk << 3) + q)] =
          make_float4(r[q * 4 + 0], r[q * 4 + 1], r[q * 4 + 2], r[q * 4 + 3]);
    }
  }
  __syncthreads();

  for (int k = 64; k <= NMAPS; k <<= 1) {
    for (int j = k >> 1; j >= 32; j >>= 1) {
      const int j4 = j >> 2;
      const int kq = k >> 2;
#pragma unroll
      for (int q = 0; q < 8; ++q) {
        const int g = tid + (q << 8);
        const int row = g >> 7;
        const int v = g & 127;
        const int i4 = ((v & ~(j4 - 1)) << 1) | (v & (j4 - 1));
        const bool desc = ((i4 & kq) == 0);
        const int ia = sw4(row, i4);
        const int ib = sw4(row, i4 + j4);
        float4 va = S4[ia];
        float4 vb = S4[ib];
        float4 lo, hi;
        lo.x = fminf(va.x, vb.x); hi.x = fmaxf(va.x, vb.x);
        lo.y = fminf(va.y, vb.y); hi.y = fmaxf(va.y, vb.y);
        lo.z = fminf(va.z, vb.z); hi.z = fmaxf(va.z, vb.z);
        lo.w = fminf(va.w, vb.w); hi.w = fmaxf(va.w, vb.w);
        S4[ia] = desc ? hi : lo;
        S4[ib] = desc ? lo : hi;
      }
      __syncthreads();
    }
#pragma unroll
    for (int c = 0; c < 2; ++c) {
      const int cid = tid + (c << 8);
      const int row = cid >> 5;
      const int chunk = cid & 31;
      const bool D = (((chunk << 5) & k) == 0);
      float r[32];
#pragma unroll
      for (int q = 0; q < 8; ++q) {
        float4 t = S4[sw4(row, (chunk << 3) + q)];
        r[q * 4 + 0] = t.x; r[q * 4 + 1] = t.y; r[q * 4 + 2] = t.z; r[q * 4 + 3] = t.w;
      }
#pragma unroll
      for (int j = 16; j > 0; j >>= 1) {
#pragma unroll
        for (int i = 0; i < 32; ++i) {
          if ((i & j) == 0) ce(r[i], r[i | j], D);
        }
      }
#pragma unroll
      for (int q = 0; q < 8; ++q) {
        S4[sw4(row, (chunk << 3) + q)] =
            make_float4(r[q * 4 + 0], r[q * 4 + 1], r[q * 4 + 2], r[q * 4 + 3]);
      }
    }
    __syncthreads();
  }

  const int p = tid;
  const int rank = (int)rint(1.0 + (double)p * (1022.0 / 255.0));
#pragma unroll
  for (int m = 0; m < TM; ++m) {
    out[((size_t)(b * NMAPS + m0 + m) << 8) + p] = lds[sw4(m, rank >> 2) * 4 + (rank & 3)];
  }
}

extern "C" void kernel_launch(void* const* d_in, const int* in_sizes, int n_in,
                              void* d_out, int out_size, void* d_ws, size_t ws_size,
                              hipStream_t stream) {
  const float* x = reinterpret_cast<const float*>(d_in[0]);
  float* out = reinterpret_cast<float*>(d_out);
  const int nelem = in_sizes[0];
  const int B = nelem / (NMAPS * FDIM);  // 32
  const size_t need_split = (size_t)nelem * 2 + (size_t)B * NMAPS * NMAPS * 2;  // 96 MB
  if (ws_size >= need_split) {
    short* xw = reinterpret_cast<short*>(d_ws);
    unsigned* corrW = reinterpret_cast<unsigned*>((char*)d_ws + (size_t)nelem * 2);
    const int n8 = nelem / 8;
    hipLaunchKernelGGL(cvt_bf16_kernel, dim3((n8 + 255) / 256), dim3(256), 0, stream, x, xw, n8);
    hipLaunchKernelGGL(corr_gemm_tiled, dim3(64 * B), dim3(256), 0, stream, xw, corrW);
    hipLaunchKernelGGL(sort_rows_kernel, dim3(B * NMAPS / 8), dim3(256), 0, stream, corrW, out);
  } else if (ws_size >= (size_t)nelem * 2) {
    short* xw = reinterpret_cast<short*>(d_ws);
    const int n8 = nelem / 8;
    hipLaunchKernelGGL(cvt_bf16_kernel, dim3((n8 + 255) / 256), dim3(256), 0, stream, x, xw, n8);
    hipLaunchKernelGGL(selfcorr_mfma_kernel, dim3(NMAPS / TM, B), dim3(NT), 0, stream, xw, out);
  } else {
    hipLaunchKernelGGL(selfcorr_pool_kernel, dim3(NMAPS / TM, B), dim3(NT), 0, stream, x, out);
  }
}

// Round 15
// 149.739 us; speedup vs baseline: 1.0924x; 1.0222x over previous
//
#include <hip/hip_runtime.h>

// SelfCorrelationPercPooling: x (32,32,32,512) f32 ->
//   corr[b] = X·Xᵀ/512 (1024x1024), per-row descending sort, gather 256 ranks.
// v15 = v14 with A-fragments loaded DIRECTLY from L2 into registers (A rows are
//   wave-private, re-used every kt -> LDS staging for A was pure overhead):
//   LDS 32->16 KB (B only), gload_lds/thread/kt 4->2, LDS reads/wave/kt 10->8,
//   occupancy cap 33->~70%. A-regs double-buffered; counted-vmcnt(4) covers both
//   last iter's B-stage and A-load (same 2-barrier race analysis as v13/v14).
// Pipeline: cvt(bf16) -> corr_gemm_tiled (sorted 128-run epilogue) -> sort_rows.
// Fallbacks: ws>=32MB -> v5 fused kernel; else v1 fp32 kernel.

#define NMAPS 1024
#define FDIM 512
#define TM 16
#define NT 256

typedef __attribute__((ext_vector_type(8))) short short8_t;   // bf16x8 MFMA frag
typedef __attribute__((ext_vector_type(4))) float f32x4;
typedef __attribute__((ext_vector_type(16))) float f32x16;    // 32x32 accumulator
typedef _Float16 h2 __attribute__((ext_vector_type(2)));      // packed fp16 pair

#define SELD 0x03020504u  // perm selector: (mx.lo16, mn.hi16) = desc pair
#define SELA 0x07060100u  // perm selector: (mn.lo16, mx.hi16) = asc pair

__device__ __forceinline__ h2 h2min(h2 a, h2 b) { return __builtin_elementwise_min(a, b); }
__device__ __forceinline__ h2 h2max(h2 a, h2 b) { return __builtin_elementwise_max(a, b); }

__device__ __forceinline__ unsigned h2u(h2 x) { union { h2 h; unsigned u; } t; t.h = x; return t.u; }
__device__ __forceinline__ h2 u2h(unsigned x) { union { h2 h; unsigned u; } t; t.u = x; return t.h; }

__device__ __forceinline__ h2 h2swap(h2 v) {
  unsigned u = h2u(v);
  return u2h((u >> 16) | (u << 16));
}

__device__ __forceinline__ h2 h2shfl_xor(h2 v, int m) {
  union { h2 h; int i; } u;
  u.h = v;
  u.i = __shfl_xor(u.i, m, 64);
  return u.h;
}

// packed word-pair CE, runtime direction
__device__ __forceinline__ void ce_pair(h2& a, h2& b, bool d) {
  h2 mn = h2min(a, b), mx = h2max(a, b);
  a = d ? mx : mn;
  b = d ? mn : mx;
}

// within-word CE (element stride 1) via perm selector (sel = SELD or SELA)
__device__ __forceinline__ h2 ce1(h2 w, unsigned sel) {
  h2 s = h2swap(w);
  h2 mn = h2min(w, s), mx = h2max(w, s);
#if __has_builtin(__builtin_amdgcn_perm)
  return u2h(__builtin_amdgcn_perm(h2u(mx), h2u(mn), sel));
#else
  h2 rd; rd[0] = mx[0]; rd[1] = mn[1];
  h2 ra; ra[0] = mn[0]; ra[1] = mx[1];
  return (sel == SELD) ? rd : ra;
#endif
}

// intra-lane merge of a 16-run (levels j=8,4,2,1), uniform direction d
__device__ __forceinline__ void intra_merge16(h2 w[8], bool d, unsigned sel) {
  ce_pair(w[0], w[4], d); ce_pair(w[1], w[5], d); ce_pair(w[2], w[6], d); ce_pair(w[3], w[7], d);
  ce_pair(w[0], w[2], d); ce_pair(w[1], w[3], d); ce_pair(w[4], w[6], d); ce_pair(w[5], w[7], d);
  ce_pair(w[0], w[1], d); ce_pair(w[2], w[3], d); ce_pair(w[4], w[5], d); ce_pair(w[6], w[7], d);
#pragma unroll
  for (int u = 0; u < 8; ++u) w[u] = ce1(w[u], sel);
}

// full bitonic sort of 16 in-lane elements, overall direction d  [verified v8-v14]
__device__ __forceinline__ void sort16(h2 w[8], bool d, unsigned sd, unsigned si) {
  w[0] = ce1(w[0], sd); w[1] = ce1(w[1], si); w[2] = ce1(w[2], sd); w[3] = ce1(w[3], si);
  w[4] = ce1(w[4], sd); w[5] = ce1(w[5], si); w[6] = ce1(w[6], sd); w[7] = ce1(w[7], si);
  ce_pair(w[0], w[1], d); ce_pair(w[2], w[3], !d); ce_pair(w[4], w[5], d); ce_pair(w[6], w[7], !d);
  w[0] = ce1(w[0], sd); w[1] = ce1(w[1], sd); w[2] = ce1(w[2], si); w[3] = ce1(w[3], si);
  w[4] = ce1(w[4], sd); w[5] = ce1(w[5], sd); w[6] = ce1(w[6], si); w[7] = ce1(w[7], si);
  ce_pair(w[0], w[2], d); ce_pair(w[1], w[3], d); ce_pair(w[4], w[6], !d); ce_pair(w[5], w[7], !d);
  ce_pair(w[0], w[1], d); ce_pair(w[2], w[3], d); ce_pair(w[4], w[5], !d); ce_pair(w[6], w[7], !d);
  w[0] = ce1(w[0], sd); w[1] = ce1(w[1], sd); w[2] = ce1(w[2], sd); w[3] = ce1(w[3], sd);
  w[4] = ce1(w[4], si); w[5] = ce1(w[5], si); w[6] = ce1(w[6], si); w[7] = ce1(w[7], si);
  intra_merge16(w, d, sd);
}

// in-lane bitonic merge of 32 elements (16 words), uniform direction d
__device__ __forceinline__ void merge32(h2 w[16], bool d) {
  const unsigned sel = d ? SELD : SELA;
#pragma unroll
  for (int u = 0; u < 8; ++u) ce_pair(w[u], w[u + 8], d);          // j=16
#pragma unroll
  for (int u = 0; u < 16; ++u)
    if ((u & 4) == 0) ce_pair(w[u], w[u | 4], d);                  // j=8
#pragma unroll
  for (int u = 0; u < 16; ++u)
    if ((u & 2) == 0) ce_pair(w[u], w[u | 2], d);                  // j=4
#pragma unroll
  for (int u = 0; u < 16; ++u)
    if ((u & 1) == 0) ce_pair(w[u], w[u | 1], d);                  // j=2
#pragma unroll
  for (int u = 0; u < 16; ++u) w[u] = ce1(w[u], sel);              // j=1
}

// in-lane bitonic merge of 64 elements (32 words), uniform direction d
__device__ __forceinline__ void merge64(h2 w[32], bool d) {
  const unsigned sel = d ? SELD : SELA;
#pragma unroll
  for (int u = 0; u < 16; ++u) ce_pair(w[u], w[u + 16], d);        // j=32
#pragma unroll
  for (int u = 0; u < 32; ++u)
    if ((u & 8) == 0) ce_pair(w[u], w[u | 8], d);                  // j=16
#pragma unroll
  for (int u = 0; u < 32; ++u)
    if ((u & 4) == 0) ce_pair(w[u], w[u | 4], d);                  // j=8
#pragma unroll
  for (int u = 0; u < 32; ++u)
    if ((u & 2) == 0) ce_pair(w[u], w[u | 2], d);                  // j=4
#pragma unroll
  for (int u = 0; u < 32; ++u)
    if ((u & 1) == 0) ce_pair(w[u], w[u | 1], d);                  // j=2
#pragma unroll
  for (int u = 0; u < 32; ++u) w[u] = ce1(w[u], sel);              // j=1
}

// cross-lane CE over N words (shuffle mask m), uniform keepmax
template<int N>
__device__ __forceinline__ void cross_ceN(h2* w, int m, bool keepmax) {
#pragma unroll
  for (int u = 0; u < N; ++u) {
    h2 p = h2shfl_xor(w[u], m);
    h2 mn = h2min(w[u], p), mx = h2max(w[u], p);
    w[u] = keepmax ? mx : mn;
  }
}
__device__ __forceinline__ void cross_ce(h2 w[8], int m, bool keepmax) {
  cross_ceN<8>(w, m, keepmax);
}

// One bitonic stage (block size K) on 1024 elements held as 8 h2/lane.
// Element i = lane*16 + 2*u + h. desc = ((i & K) == 0). [verified v5/v6/v7]
template<int K>
__device__ __forceinline__ void bitonic_stage(h2 w8[8], int lane) {
  const bool laneDesc = (K >= 16) ? ((lane & (K >> 4)) == 0) : true;
#pragma unroll
  for (int j = 512; j >= 16; j >>= 1) {
    if (j > (K >> 1)) continue;
    const int m = j >> 4;
    const bool keepmax = (((lane & m) == 0) == laneDesc);
#pragma unroll
    for (int u = 0; u < 8; ++u) {
      h2 p = h2shfl_xor(w8[u], m);
      h2 mn = h2min(w8[u], p), mx = h2max(w8[u], p);
      w8[u] = keepmax ? mx : mn;
    }
  }
#pragma unroll
  for (int j = 8; j >= 2; j >>= 1) {
    if (j > (K >> 1)) continue;
    const int jw = j >> 1;
#pragma unroll
    for (int u = 0; u < 8; ++u) {
      if ((u & jw) == 0) {
        const int v = u | jw;
        const bool desc = (K <= 8) ? (((2 * u) & K) == 0) : laneDesc;
        h2 mn = h2min(w8[u], w8[v]), mx = h2max(w8[u], w8[v]);
        w8[u] = desc ? mx : mn;
        w8[v] = desc ? mn : mx;
      }
    }
  }
#pragma unroll
  for (int u = 0; u < 8; ++u) {
    const bool desc = (K <= 8) ? (((2 * u) & K) == 0) : laneDesc;
    h2 s = h2swap(w8[u]);
    h2 mn = h2min(w8[u], s), mx = h2max(w8[u], s);
    h2 rd = (h2){mx[0], mn[1]};
    h2 ra = (h2){mn[0], mx[1]};
    w8[u] = desc ? rd : ra;
  }
}

// tail stage (K >= 128 only), TWO independent rows interleaved for ILP
template<int K>
__device__ __forceinline__ void bitonic_stage_tail2(h2 A[8], h2 B[8], int lane) {
  const bool laneDesc = ((lane & (K >> 4)) == 0);
#pragma unroll
  for (int j = 512; j >= 16; j >>= 1) {
    if (j > (K >> 1)) continue;
    const int m = j >> 4;
    const bool km = (((lane & m) == 0) == laneDesc);
    cross_ce(A, m, km);
    cross_ce(B, m, km);
  }
  const unsigned sel = laneDesc ? SELD : SELA;
  intra_merge16(A, laneDesc, sel);
  intra_merge16(B, laneDesc, sel);
}

__device__ __forceinline__ void run_bitonic(h2 w8[8], int lane) {  // full (fallbacks)
  bitonic_stage<2>(w8, lane);
  bitonic_stage<4>(w8, lane);
  bitonic_stage<8>(w8, lane);
  bitonic_stage<16>(w8, lane);
  bitonic_stage<32>(w8, lane);
  bitonic_stage<64>(w8, lane);
  bitonic_stage<128>(w8, lane);
  bitonic_stage<256>(w8, lane);
  bitonic_stage<512>(w8, lane);
  bitonic_stage<1024>(w8, lane);
}

// ---------------- fp32 -> bf16 (RNE) conversion pre-pass ----------------
__global__ __launch_bounds__(256) void cvt_bf16_kernel(const float* __restrict__ x,
                                                       short* __restrict__ xw, int n8) {
  int i = blockIdx.x * 256 + threadIdx.x;
  if (i >= n8) return;
  const float4* x4 = reinterpret_cast<const float4*>(x);
  float4 a = x4[i * 2], c = x4[i * 2 + 1];
  float f[8] = {a.x, a.y, a.z, a.w, c.x, c.y, c.z, c.w};
  union { short8_t v; short s[8]; } o;
#pragma unroll
  for (int j = 0; j < 8; ++j) {
    unsigned u = __float_as_uint(f[j]);
    u += 0x7fffu + ((u >> 16) & 1u);  // RNE (no NaN in data)
    o.s[j] = (short)(u >> 16);
  }
  reinterpret_cast<short8_t*>(xw)[i] = o.v;
}

// ---------------- kernel 2: TILED 32x32x16 MFMA GEMM, A-from-L2, B in LDS ----------------
// 128x128 C-tile/block, 4 waves x 4 (32x32) tiles, BK=32 (2 K-steps of 16).
// A-fragments: direct global loads (wave-private rows, L2-resident; double-buffered
// in regs). B-tile: gload_lds staged with source swizzle s^=(r>>1)&3 (verified).
// K-loop: barA -> STAGE_B(next)+LOAD_A(next) -> vmcnt(4) -> barB -> reads+MFMA.
// Epilogue: in-lane sort64 + lane^32 cross + merge64 -> sorted 128-run (v14, verified).
__global__ __launch_bounds__(256) void corr_gemm_tiled(const short* __restrict__ xw,
                                                       unsigned* __restrict__ corrW) {
  __shared__ short Bsm[2][128 * 32];  // 2 x 8 KB (B only)
  const int tid = threadIdx.x;
  int b, tile;
  if (gridDim.x == 2048) {
    const int bid = blockIdx.x;
    const int xcd = bid & 7;       // dispatch round-robins across 8 XCDs
    const int j = bid >> 3;        // 0..255
    b = (j >> 6) * 8 + xcd;        // 4 batches per XCD -> L2-resident panels
    tile = j & 63;
  } else {
    b = blockIdx.x >> 6;
    tile = blockIdx.x & 63;
  }
  const int it = tile >> 3, jt = tile & 7;
  const int i0 = it * 128, j0 = jt * 128;
  const int lane = tid & 63;
  const int w = tid >> 6;        // wave 0..3 (owns rows [i0+32w, +32))
  const int lr32 = lane & 31;    // operand row within 32-row group
  const int hi = lane >> 5;      // k-half / col-phase
  const short* Xb = xw + (size_t)b * NMAPS * FDIM;

  // B staging: 2 chunk-slots per thread (512 chunks = 128x32 tile)
  int srcOff[2], dstOff[2];
  {
    const int idxs[2] = {tid, tid + 256};
#pragma unroll
    for (int rp = 0; rp < 2; ++rp) {
      const int r = idxs[rp] >> 2;
      const int s = (idxs[rp] & 3) ^ ((r >> 1) & 3);  // pre-swizzled source chunk
      srcOff[rp] = r * FDIM + s * 8;
      dstOff[rp] = idxs[rp] * 8;
    }
  }

  // B read offsets (shorts): chunk = 2*ks + hi; addr = row*32 + (chunk ^ swz(row))*8
  int bOff[4][2];
#pragma unroll
  for (int tc = 0; tc < 4; ++tc) {
    const int rb = tc * 32 + lr32;
#pragma unroll
    for (int ks = 0; ks < 2; ++ks)
      bOff[tc][ks] = rb * 32 + (((2 * ks + hi) ^ ((rb >> 1) & 3)) * 8);
  }

  // A direct-load base: row i0 + w*32 + lr32, chunk (2ks+hi) -> byte-contiguous 16B
  const short* gAbase = Xb + (size_t)(i0 + w * 32 + lr32) * FDIM + hi * 8;
  // A(kt, ks) at gAbase + kt*32 + ks*16

  f32x16 acc[4];
#pragma unroll
  for (int tc = 0; tc < 4; ++tc)
#pragma unroll
    for (int q = 0; q < 16; ++q) acc[tc][q] = 0.f;

#define STAGE_B(buf, kt)                                                               \
  {                                                                                    \
    _Pragma("unroll") for (int rp = 0; rp < 2; ++rp) {                                 \
      const short* gB = Xb + (size_t)j0 * FDIM + srcOff[rp] + (kt) * 32;               \
      __builtin_amdgcn_global_load_lds(                                                \
          (const __attribute__((address_space(1))) unsigned*)gB,                       \
          (__attribute__((address_space(3))) unsigned*)(Bsm[buf] + dstOff[rp]), 16,    \
          0, 0);                                                                       \
    }                                                                                  \
  }
#define LOAD_A(d0, d1, kt)                                                             \
  {                                                                                    \
    d0 = *reinterpret_cast<const short8_t*>(gAbase + (kt) * 32);                       \
    d1 = *reinterpret_cast<const short8_t*>(gAbase + (kt) * 32 + 16);                  \
  }
#define SBAR() __builtin_amdgcn_sched_barrier(0)
#define BARRIER()                      \
  {                                    \
    SBAR();                            \
    __builtin_amdgcn_s_barrier();      \
    SBAR();                            \
  }

  short8_t aCur0, aCur1, aNxt0, aNxt1;
  STAGE_B(0, 0);
  LOAD_A(aCur0, aCur1, 0);

  for (int kt = 0; kt < 16; ++kt) {
    const int cur = kt & 1;
    BARRIER();  // A: prev iter's readers of Bsm[cur^1] done (lgkm forced by MFMAs)
    if (kt < 15) {
      STAGE_B(cur ^ 1, kt + 1);       // 2 gload_lds into freed buffer
      LOAD_A(aNxt0, aNxt1, kt + 1);   // 2 reg loads (next iter's A)
      SBAR();
      asm volatile("s_waitcnt vmcnt(4)" ::: "memory");  // last iter's B+A landed
    } else {
      SBAR();
      asm volatile("s_waitcnt vmcnt(0)" ::: "memory");
    }
    BARRIER();  // B: ALL waves' cur B-loads landed -> safe to ds_read

#pragma unroll
    for (int ks = 0; ks < 2; ++ks) {
      const short8_t a = (ks == 0) ? aCur0 : aCur1;
      short8_t bf[4];
#pragma unroll
      for (int tc = 0; tc < 4; ++tc)
        bf[tc] = *reinterpret_cast<const short8_t*>(Bsm[cur] + bOff[tc][ks]);
#pragma unroll
      for (int tc = 0; tc < 4; ++tc)
        acc[tc] = __builtin_amdgcn_mfma_f32_32x32x16_bf16(bf[tc], a, acc[tc], 0, 0, 0);
    }
    aCur0 = aNxt0;
    aCur1 = aNxt1;
  }
#undef STAGE_B
#undef LOAD_A
#undef BARRIER
#undef SBAR

  // ---- epilogue: lane's 64 values (row i0+32w+lr32; lane-pair l/l^32 holds the
  //      full 128-col panel) -> sorted 128-run, desc iff jt even. [verified v14]
  {
    const bool D = ((jt & 1) == 0);
    h2 W[32];
#pragma unroll
    for (int tc = 0; tc < 4; ++tc)
#pragma unroll
      for (int q = 0; q < 8; ++q)
        W[tc * 8 + q] = (h2){(_Float16)acc[tc][2 * q], (_Float16)acc[tc][2 * q + 1]};
    sort16(W, true, SELD, SELA);
    sort16(W + 8, false, SELA, SELD);
    merge32(W, true);                    // W[0..15] sorted desc (32)
    sort16(W + 16, true, SELD, SELA);
    sort16(W + 24, false, SELA, SELD);
    merge32(W + 16, false);              // W[16..31] sorted asc (32)
    merge64(W, hi == 0);                 // stage 64: desc iff hi==0
    cross_ceN<32>(W, 32, (hi == 0) == D);  // stage 128: j=64 across lane^32
    merge64(W, D);                          // j=32..1 in-lane
    const size_t roww = ((size_t)b * NMAPS + i0 + w * 32 + lr32) * 512;
    const int wq = (j0 >> 1) + hi * 32;
#pragma unroll
    for (int g = 0; g < 8; ++g) {
      union { h2 h[4]; uint4 u; } s;
#pragma unroll
      for (int q = 0; q < 4; ++q) s.h[q] = W[g * 4 + q];
      *reinterpret_cast<uint4*>(corrW + roww + wq + g * 4) = s.u;
    }
  }
}

// ---------------- kernel 3: tail sort (K=256..1024), TWO rows per wave + scatter ----------------
__global__ __launch_bounds__(256) void sort_rows_kernel(const unsigned* __restrict__ corrW,
                                                        float* __restrict__ out) {
  const int tid = threadIdx.x;
  const int lane = tid & 63;
  const int rA = blockIdx.x * 8 + (tid >> 6) * 2;  // wave handles rows rA, rA+1
  const int rB = rA + 1;
  const uint4* pa = reinterpret_cast<const uint4*>(corrW + (size_t)rA * 512);
  const uint4* pb = reinterpret_cast<const uint4*>(corrW + (size_t)rB * 512);

  h2 A[8], B[8];
  {
    union { uint4 u; h2 h[4]; } t0, t1;
    t0.u = pa[lane * 2]; t1.u = pa[lane * 2 + 1];
    A[0] = t0.h[0]; A[1] = t0.h[1]; A[2] = t0.h[2]; A[3] = t0.h[3];
    A[4] = t1.h[0]; A[5] = t1.h[1]; A[6] = t1.h[2]; A[7] = t1.h[3];
    t0.u = pb[lane * 2]; t1.u = pb[lane * 2 + 1];
    B[0] = t0.h[0]; B[1] = t0.h[1]; B[2] = t0.h[2]; B[3] = t0.h[3];
    B[4] = t1.h[0]; B[5] = t1.h[1]; B[6] = t1.h[2]; B[7] = t1.h[3];
  }

  // input: 128-runs sorted, desc iff (c&128)==0 -> start at K=256
  bitonic_stage_tail2<256>(A, B, lane);
  bitonic_stage_tail2<512>(A, B, lane);
  bitonic_stage_tail2<1024>(A, B, lane);

  float* oa = out + (size_t)rA * 256;
  float* ob = out + (size_t)rB * 256;
#pragma unroll
  for (int u = 0; u < 8; ++u) {
#pragma unroll
    for (int hh = 0; hh < 2; ++hh) {
      const int i = lane * 16 + 2 * u + hh;
      const int p = (int)rint((double)(i - 1) * (255.0 / 1022.0));
      const int rk = (int)rint(1.0 + (double)p * (1022.0 / 255.0));
      if (rk == i) {
        oa[p] = (float)A[u][hh] * (1.f / FDIM);  // deferred scale
        ob[p] = (float)B[u][hh] * (1.f / FDIM);
      }
    }
  }
}

// ---------------- v5 fused fallback (ws >= 32MB but < 96MB) ----------------
__global__ __launch_bounds__(NT) void selfcorr_mfma_kernel(const short* __restrict__ xw,
                                                           float* __restrict__ out) {
  __shared__ alignas(16) h2 SH[TM * 512];  // 32 KB
  const int tid = threadIdx.x;
  const int b = blockIdx.y;
  const int m0 = blockIdx.x * TM;
  const int lane = tid & 63;
  const int wid = tid >> 6;
  const int lr = lane & 15;
  const int kg = lane >> 4;
  const int wc = wid * 256;
  const short* Xb = xw + (size_t)b * NMAPS * FDIM;

  f32x4 acc[16];
#pragma unroll
  for (int t = 0; t < 16; ++t) acc[t] = (f32x4){0.f, 0.f, 0.f, 0.f};

  for (int kk = 0; kk < 16; ++kk) {
    const short8_t* base = reinterpret_cast<const short8_t*>(Xb + kk * 32 + kg * 8);
    short8_t afrag = base[(size_t)(m0 + lr) * 64];
    short8_t bfrag[16];
#pragma unroll
    for (int t = 0; t < 16; ++t) bfrag[t] = base[(size_t)(wc + t * 16 + lr) * 64];
#pragma unroll
    for (int t = 0; t < 16; ++t)
      acc[t] = __builtin_amdgcn_mfma_f32_16x16x32_bf16(bfrag[t], afrag, acc[t], 0, 0, 0);
  }

  {
    const int xorv = (lr & 7) << 2;
#pragma unroll
    for (int t = 0; t < 16; ++t) {
      h2 lo = (h2){(_Float16)(acc[t][0] * (1.f / FDIM)), (_Float16)(acc[t][1] * (1.f / FDIM))};
      h2 hi = (h2){(_Float16)(acc[t][2] * (1.f / FDIM)), (_Float16)(acc[t][3] * (1.f / FDIM))};
      const int W = (wc >> 1) + t * 8 + kg * 2;
      const int phys = lr * 512 + (W ^ xorv);
      union { h2 h[2]; uint2 u; } pk;
      pk.h[0] = lo; pk.h[1] = hi;
      *reinterpret_cast<uint2*>(&SH[phys]) = pk.u;
    }
  }
  __syncthreads();

  const int rowbase = wid * 4;
  for (int rr = rowbase; rr < rowbase + 4; ++rr) {
    const int rx = (rr & 7) << 2;
    h2 w8[8];
#pragma unroll
    for (int q = 0; q < 2; ++q) {
      const int p4 = rr * 512 + ((lane * 8 + q * 4) ^ rx);
      union { uint4 u; h2 h[4]; } un;
      un.u = *reinterpret_cast<const uint4*>(&SH[p4]);
      w8[q * 4 + 0] = un.h[0]; w8[q * 4 + 1] = un.h[1];
      w8[q * 4 + 2] = un.h[2]; w8[q * 4 + 3] = un.h[3];
    }
    run_bitonic(w8, lane);
#pragma unroll
    for (int q = 0; q < 2; ++q) {
      const int p4 = rr * 512 + ((lane * 8 + q * 4) ^ rx);
      union { uint4 u; h2 h[4]; } un;
      un.h[0] = w8[q * 4 + 0]; un.h[1] = w8[q * 4 + 1];
      un.h[2] = w8[q * 4 + 2]; un.h[3] = w8[q * 4 + 3];
      *reinterpret_cast<uint4*>(&SH[p4]) = un.u;
    }
  }
  __builtin_amdgcn_wave_barrier();

#pragma unroll
  for (int i = 0; i < 16; ++i) {
    const int rr = rowbase + (i >> 2);
    const int p = lane + ((i & 3) << 6);
    const int rank = (int)rint(1.0 + (double)p * (1022.0 / 255.0));
    const int Wr = (rank >> 1) ^ ((rr & 7) << 2);
    h2 hv = SH[rr * 512 + Wr];
    out[((size_t)(b * NMAPS + m0 + rr) << 8) + p] = (float)hv[rank & 1];
  }
}

// ---------------- v1 fp32 fallback (ws too small) ----------------
__device__ __forceinline__ int sw4(int row, int c4) {
  return (row << 8) | (c4 ^ ((c4 >> 3) & 7));
}
__device__ __forceinline__ void ce(float& a, float& b, bool desc) {
  float mn = fminf(a, b);
  float mx = fmaxf(a, b);
  a = desc ? mx : mn;
  b = desc ? mn : mx;
}

__global__ __launch_bounds__(NT) void selfcorr_pool_kernel(const float* __restrict__ x,
                                                           float* __restrict__ out) {
  __shared__ float lds[TM * NMAPS];
  float4* S4 = reinterpret_cast<float4*>(lds);
  const int tid = threadIdx.x;
  const int b = blockIdx.y;
  const int m0 = blockIdx.x * TM;
  const float4* Xb = reinterpret_cast<const float4*>(x) + (size_t)b * NMAPS * (FDIM / 4);

  float4* A4 = reinterpret_cast<float4*>(lds);
#pragma unroll
  for (int idx = tid; idx < TM * (FDIM / 4); idx += NT) {
    A4[idx] = Xb[(m0 + (idx >> 7)) * 128 + (idx & 127)];
  }
  __syncthreads();

  float acc[TM][4];
#pragma unroll
  for (int m = 0; m < TM; ++m)
#pragma unroll
    for (int j = 0; j < 4; ++j) acc[m][j] = 0.0f;

  float4 nb0 = Xb[(tid + 0) * 128];
  float4 nb1 = Xb[(tid + 256) * 128];
  float4 nb2 = Xb[(tid + 512) * 128];
  float4 nb3 = Xb[(tid + 768) * 128];
  for (int k4 = 0; k4 < 128; ++k4) {
    float4 b0 = nb0, b1 = nb1, b2 = nb2, b3 = nb3;
    const int kn = (k4 < 127) ? (k4 + 1) : 127;
    nb0 = Xb[(tid + 0) * 128 + kn];
    nb1 = Xb[(tid + 256) * 128 + kn];
    nb2 = Xb[(tid + 512) * 128 + kn];
    nb3 = Xb[(tid + 768) * 128 + kn];
#pragma unroll
    for (int m = 0; m < TM; ++m) {
      float4 a = A4[m * 128 + k4];
      acc[m][0] += a.x * b0.x + a.y * b0.y + a.z * b0.z + a.w * b0.w;
      acc[m][1] += a.x * b1.x + a.y * b1.y + a.z * b1.z + a.w * b1.w;
      acc[m][2] += a.x * b2.x + a.y * b2.y + a.z * b2.z + a.w * b2.w;
      acc[m][3] += a.x * b3.x + a.y * b3.y + a.z * b3.z + a.w * b3.w;
    }
  }
  __syncthreads();

#pragma unroll
  for (int m = 0; m < TM; ++m) {
#pragma unroll
    for (int j = 0; j < 4; ++j) {
      const int n = tid + (j << 8);
      lds[sw4(m, n >> 2) * 4 + (n & 3)] = acc[m][j] * (1.0f / FDIM);
    }
  }
  __syncthreads();

#pragma unroll
  for (int c = 0; c < 2; ++c) {
    const int cid = tid + (c << 8);
    const int row = cid >> 5;
    const int chunk = cid & 31;
    float r[32];
#pragma unroll
    for (int q = 0; q < 8; ++q) {
      float4 t = S4[sw4(row, (chunk << 3) + q)];
      r[q * 4 + 0] = t.x; r[q * 4 + 1] = t.y; r[q * 4 + 2] = t.z; r[q * 4 + 3] = t.w;
    }
    const bool D = ((chunk & 1) == 0);
#pragma unroll
    for (int k2 = 2; k2 <= 32; k2 <<= 1) {
#pragma unroll
      for (int j = k2 >> 1; j > 0; j >>= 1) {
#pragma unroll
        for (int i = 0; i < 32; ++i) {
          if ((i & j) == 0) ce(r[i], r[i | j], ((i & k2) == 0) ? D : !D);
        }
      }
    }
#pragma unroll
    for (int q = 0; q < 8; ++q) {
      S4[sw4(row, (chunk << 3) + q)] =
          make_float4(r[q * 4 + 0], r[q * 4 + 1], r[q * 4 + 2], r[q * 4 + 3]);
    }
  }
  __syncthreads();

  for (int k = 64; k <= NMAPS; k <<= 1) {
    for (int j = k >> 1; j >= 32; j >>= 1) {
      const int j4 = j >> 2;
      const int kq = k >> 2;
#pragma unroll
      for (int q = 0; q < 8; ++q) {
        const int g = tid + (q << 8);
        const int row = g >> 7;
        const int v = g & 127;
        const int i4 = ((v & ~(j4 - 1)) << 1) | (v & (j4 - 1));
        const bool desc = ((i4 & kq) == 0);
        const int ia = sw4(row, i4);
        const int ib = sw4(row, i4 + j4);
        float4 va = S4[ia];
        float4 vb = S4[ib];
        float4 lo, hi;
        lo.x = fminf(va.x, vb.x); hi.x = fmaxf(va.x, vb.x);
        lo.y = fminf(va.y, vb.y); hi.y = fmaxf(va.y, vb.y);
        lo.z = fminf(va.z, vb.z); hi.z = fmaxf(va.z, vb.z);
        lo.w = fminf(va.w, vb.w); hi.w = fmaxf(va.w, vb.w);
        S4[ia] = desc ? hi : lo;
        S4[ib] = desc ? lo : hi;
      }
      __syncthreads();
    }
#pragma unroll
    for (int c = 0; c < 2; ++c) {
      const int cid = tid + (c << 8);
      const int row = cid >> 5;
      const int chunk = cid & 31;
      const bool D = (((chunk << 5) & k) == 0);
      float r[32];
#pragma unroll
      for (int q = 0; q < 8; ++q) {
        float4 t = S4[sw4(row, (chunk << 3) + q)];
        r[q * 4 + 0] = t.x; r[q * 4 + 1] = t.y; r[q * 4 + 2] = t.z; r[q * 4 + 3] = t.w;
      }
#pragma unroll
      for (int j = 16; j > 0; j >>= 1) {
#pragma unroll
        for (int i = 0; i < 32; ++i) {
          if ((i & j) == 0) ce(r[i], r[i | j], D);
        }
      }
#pragma unroll
      for (int q = 0; q < 8; ++q) {
        S4[sw4(row, (chunk << 3) + q)] =
            make_float4(r[q * 4 + 0], r[q * 4 + 1], r[q * 4 + 2], r[q * 4 + 3]);
      }
    }
    __syncthreads();
  }

  const int p = tid;
  const int rank = (int)rint(1.0 + (double)p * (1022.0 / 255.0));
#pragma unroll
  for (int m = 0; m < TM; ++m) {
    out[((size_t)(b * NMAPS + m0 + m) << 8) + p] = lds[sw4(m, rank >> 2) * 4 + (rank & 3)];
  }
}

extern "C" void kernel_launch(void* const* d_in, const int* in_sizes, int n_in,
                              void* d_out, int out_size, void* d_ws, size_t ws_size,
                              hipStream_t stream) {
  const float* x = reinterpret_cast<const float*>(d_in[0]);
  float* out = reinterpret_cast<float*>(d_out);
  const int nelem = in_sizes[0];
  const int B = nelem / (NMAPS * FDIM);  // 32
  const size_t need_split = (size_t)nelem * 2 + (size_t)B * NMAPS * NMAPS * 2;  // 96 MB
  if (ws_size >= need_split) {
    short* xw = reinterpret_cast<short*>(d_ws);
    unsigned* corrW = reinterpret_cast<unsigned*>((char*)d_ws + (size_t)nelem * 2);
    const int n8 = nelem / 8;
    hipLaunchKernelGGL(cvt_bf16_kernel, dim3((n8 + 255) / 256), dim3(256), 0, stream, x, xw, n8);
    hipLaunchKernelGGL(corr_gemm_tiled, dim3(64 * B), dim3(256), 0, stream, xw, corrW);
    hipLaunchKernelGGL(sort_rows_kernel, dim3(B * NMAPS / 8), dim3(256), 0, stream, corrW, out);
  } else if (ws_size >= (size_t)nelem * 2) {
    short* xw = reinterpret_cast<short*>(d_ws);
    const int n8 = nelem / 8;
    hipLaunchKernelGGL(cvt_bf16_kernel, dim3((n8 + 255) / 256), dim3(256), 0, stream, x, xw, n8);
    hipLaunchKernelGGL(selfcorr_mfma_kernel, dim3(NMAPS / TM, B), dim3(NT), 0, stream, xw, out);
  } else {
    hipLaunchKernelGGL(selfcorr_pool_kernel, dim3(NMAPS / TM, B), dim3(NT), 0, stream, x, out);
  }
}